// Round 2
// baseline (6298.401 us; speedup 1.0000x reference)
//
#include <hip/hip_runtime.h>
#include <hip/hip_bf16.h>
#include <type_traits>

#define N_NODES 100000
#define N_EDGES 1600000
#define N_GRAPH 128
#define CHUNK   25088   // X2/GEMM row chunk (multiple of 64)

// ---------- bf16 <-> f32 helpers (storage type may be ushort-bf16) ----------
__device__ __forceinline__ float bf2f(unsigned short u) {
  unsigned int v = ((unsigned int)u) << 16;
  float f; __builtin_memcpy(&f, &v, 4); return f;
}
__device__ __forceinline__ unsigned short f2bf(float f) {
  unsigned int v; __builtin_memcpy(&v, &f, 4);
  unsigned int r = (v + 0x7FFFu + ((v >> 16) & 1u)) >> 16;
  return (unsigned short)r;
}
template<typename ST> __device__ __forceinline__ float ldf(const ST* p) {
  if constexpr (std::is_same_v<ST, float>) return *p;
  else return bf2f(*p);
}
template<typename ST> __device__ __forceinline__ void stf(ST* p, float v) {
  if constexpr (std::is_same_v<ST, float>) *p = v;
  else *p = f2bf(v);
}
template<typename ST, int VEC>
__device__ __forceinline__ void loadN(const ST* p, float* o) {
  ST tmp[VEC];
  __builtin_memcpy(tmp, p, VEC * sizeof(ST));   // vector load
#pragma unroll
  for (int i = 0; i < VEC; ++i) o[i] = ldf(&tmp[i]);
}
template<typename ST, int VEC>
__device__ __forceinline__ void storeN(ST* p, const float* v) {
  ST tmp[VEC];
#pragma unroll
  for (int i = 0; i < VEC; ++i) stf(&tmp[i], v[i]);
  __builtin_memcpy(p, tmp, VEC * sizeof(ST));
}

// ---------------- graph preprocessing ----------------
__global__ void k_deg(const int* __restrict__ dst, int* __restrict__ degi) {
  int e = blockIdx.x * 256 + threadIdx.x;
  if (e < N_EDGES) atomicAdd(&degi[dst[e]], 1);
}

__global__ void k_norm(const int* __restrict__ degi, float* __restrict__ nrm) {
  int i = blockIdx.x * 256 + threadIdx.x;
  if (i < N_NODES) {
    int d = degi[i]; if (d < 1) d = 1;
    nrm[i] = 1.0f / sqrtf((float)d);
  }
}

__global__ void k_scan(const int* __restrict__ degi, int* __restrict__ rowptr) {
  __shared__ int sm[1024];
  __shared__ int carry_s;
  if (threadIdx.x == 0) carry_s = 0;
  __syncthreads();
  for (int base = 0; base < N_NODES; base += 1024) {
    int c = carry_s;
    int i = base + threadIdx.x;
    int v = (i < N_NODES) ? degi[i] : 0;
    sm[threadIdx.x] = v;
    __syncthreads();
    for (int off = 1; off < 1024; off <<= 1) {
      int t = (threadIdx.x >= off) ? sm[threadIdx.x - off] : 0;
      __syncthreads();
      sm[threadIdx.x] += t;
      __syncthreads();
    }
    if (i < N_NODES) rowptr[i] = c + sm[threadIdx.x] - v;  // exclusive
    int tot = sm[1023];
    __syncthreads();
    if (threadIdx.x == 0) carry_s = c + tot;
    __syncthreads();
  }
  if (threadIdx.x == 0) rowptr[N_NODES] = carry_s;
}

__global__ void k_scatter(const int* __restrict__ src, const int* __restrict__ dst,
                          const int* __restrict__ rowptr, int* __restrict__ cursor,
                          int* __restrict__ colidx) {
  int e = blockIdx.x * 256 + threadIdx.x;
  if (e >= N_EDGES) return;
  int d = dst[e];
  int p = atomicAdd(&cursor[d], 1);
  colidx[rowptr[d] + p] = src[e];
}

__global__ void k_cast(const float* __restrict__ in, unsigned short* __restrict__ out, int n) {
  int i = blockIdx.x * 256 + threadIdx.x;
  if (i < n) out[i] = f2bf(in[i]);
}

// ---------------- Ahat aggregation (one wave per node) ----------------
// out[nl] = alpha * nrm[node] * sum_{s in in-nbrs(node)} hin[s]*nrm[s]  + beta*hadd[nl]
// node = base + nl; hin/X1 indexed globally, hadd/out indexed chunk-locally.
template<typename ST, int VEC>
__global__ void k_ahat(const ST* __restrict__ hin, const ST* __restrict__ hadd,
                       const float* __restrict__ nrm, const int* __restrict__ rowptr,
                       const int* __restrict__ colidx, ST* __restrict__ outp,
                       int F, int base, int nrows, float alpha, float beta) {
  int gtid = blockIdx.x * blockDim.x + threadIdx.x;
  int nl = gtid >> 6;
  int lane = threadIdx.x & 63;
  if (nl >= nrows) return;
  int node = base + nl;
  int e0 = rowptr[node], e1 = rowptr[node + 1];
  float acc[VEC];
#pragma unroll
  for (int v = 0; v < VEC; ++v) acc[v] = 0.f;
  for (int e = e0; e < e1; ++e) {
    int s = colidx[e];
    float ns = nrm[s];
    float hv[VEC];
    loadN<ST, VEC>(hin + (size_t)s * F + lane * VEC, hv);
#pragma unroll
    for (int v = 0; v < VEC; ++v) acc[v] += hv[v] * ns;
  }
  float sc = alpha * nrm[node];
  float res[VEC];
  if (hadd != nullptr) {
    float av[VEC];
    loadN<ST, VEC>(hadd + (size_t)nl * F + lane * VEC, av);
#pragma unroll
    for (int v = 0; v < VEC; ++v) res[v] = sc * acc[v] + beta * av[v];
  } else {
#pragma unroll
    for (int v = 0; v < VEC; ++v) res[v] = sc * acc[v];
  }
  storeN<ST, VEC>(outp + (size_t)nl * F + lane * VEC, res);
}

// ---------------- f32 tiled GEMM: relu([X0|X1|X2] @ W + b) ----------------
// POOL=true: instead of storing rows, atomicAdd into hg[gid[row]*512 + col].
template<typename ST, bool POOL>
__launch_bounds__(256)
__global__ void k_gemm3_relu(const ST* __restrict__ A0, const ST* __restrict__ A1,
                             const ST* __restrict__ A2, int F,
                             const float* __restrict__ W, const float* __restrict__ bias,
                             ST* __restrict__ outp, float* __restrict__ hg,
                             const int* __restrict__ gid, int fout, int nrows) {
  const int BM = 64, BN = 64, BKK = 16;
  __shared__ float As[BKK][BM + 4];
  __shared__ float Bs[BKK][BN + 4];
  int tid = threadIdx.x;
  int row0 = blockIdx.x * BM, col0 = blockIdx.y * BN;
  int tx = tid % 16, ty = tid / 16;
  float acc[4][4] = {{0.f}};
  int K3 = 3 * F;
  int ka = tid % 16, ma = tid / 16;   // A-load mapping
  int nb = tid % 64, kb0 = tid / 64;  // B-load mapping
  for (int k0 = 0; k0 < K3; k0 += BKK) {
    const ST* Abuf = (k0 < F) ? A0 : (k0 < 2 * F) ? A1 : A2;
    int kk = k0 % F;
#pragma unroll
    for (int r = 0; r < 4; ++r) {
      int m = ma + 16 * r;
      int row = row0 + m;
      As[ka][m] = (row < nrows) ? ldf(Abuf + (size_t)row * F + kk + ka) : 0.f;
    }
#pragma unroll
    for (int r = 0; r < 4; ++r) {
      int kb = kb0 + 4 * r;
      Bs[kb][nb] = W[(size_t)(k0 + kb) * fout + col0 + nb];
    }
    __syncthreads();
#pragma unroll
    for (int k = 0; k < BKK; ++k) {
      float a[4], b[4];
#pragma unroll
      for (int i = 0; i < 4; ++i) a[i] = As[k][ty * 4 + i];
#pragma unroll
      for (int j = 0; j < 4; ++j) b[j] = Bs[k][tx * 4 + j];
#pragma unroll
      for (int i = 0; i < 4; ++i)
#pragma unroll
        for (int j = 0; j < 4; ++j)
          acc[i][j] += a[i] * b[j];
    }
    __syncthreads();
  }
#pragma unroll
  for (int i = 0; i < 4; ++i) {
    int row = row0 + ty * 4 + i;
    if (row >= nrows) continue;
    int g = POOL ? gid[row] : 0;
#pragma unroll
    for (int j = 0; j < 4; ++j) {
      int col = col0 + tx * 4 + j;
      float v = fmaxf(acc[i][j] + bias[col], 0.f);
      if constexpr (POOL) atomicAdd(&hg[g * 512 + col], v);
      else stf(&outp[(size_t)row * fout + col], v);
    }
  }
}

// ---------------- MLP head ----------------
__global__ void k_mlp(const float* __restrict__ hg, const float* __restrict__ Wm1,
                      const float* __restrict__ bm1, const float* __restrict__ Wm2,
                      const float* __restrict__ bm2, float* __restrict__ outp) {
  __shared__ float lh[512];
  __shared__ float lt[512];
  int g = blockIdx.x, t = threadIdx.x;
  lh[t] = hg[g * 512 + t];
  __syncthreads();
  float s = bm1[t];
  for (int k = 0; k < 512; ++k) s += lh[k] * Wm1[k * 512 + t];
  lt[t] = fmaxf(s, 0.f);
  __syncthreads();
  if (t < 10) {
    float s2 = bm2[t];
    for (int j = 0; j < 512; ++j) s2 += lt[j] * Wm2[j * 10 + t];
    outp[g * 10 + t] = s2;
  }
}

// ---------------- pipeline (templated on activation storage type) ----------------
template<typename ST>
static void run_pipeline(void* const* d_in, float* outp, char* ws, hipStream_t stream) {
  const float* signal = (const float*)d_in[0];
  const float* W0 = (const float*)d_in[1];  const float* b0 = (const float*)d_in[2];
  const float* W1 = (const float*)d_in[3];  const float* b1 = (const float*)d_in[4];
  const float* W2 = (const float*)d_in[5];  const float* b2 = (const float*)d_in[6];
  const float* W3 = (const float*)d_in[7];  const float* b3 = (const float*)d_in[8];
  const float* Wm1 = (const float*)d_in[9];  const float* bm1 = (const float*)d_in[10];
  const float* Wm2 = (const float*)d_in[11]; const float* bm2 = (const float*)d_in[12];
  const int* src = (const int*)d_in[13];
  const int* dst = (const int*)d_in[14];
  const int* gid = (const int*)d_in[15];

  size_t off = 0;
  auto alloc = [&](size_t b) -> void* {
    void* p = ws + off;
    off = (off + b + 255) & ~(size_t)255;
    return p;
  };
  int* degi    = (int*)alloc((size_t)N_NODES * 4);
  float* nrm   = (float*)alloc((size_t)N_NODES * 4);
  int* rowptr  = (int*)alloc((size_t)(N_NODES + 1) * 4);
  int* cursor  = (int*)alloc((size_t)N_NODES * 4);
  int* colidx  = (int*)alloc((size_t)N_EDGES * 4);
  float* hg    = (float*)alloc((size_t)N_GRAPH * 512 * 4);
  const size_t es = sizeof(ST);
  ST* B1  = (ST*)alloc((size_t)N_NODES * 256 * es);
  ST* B2  = (ST*)alloc((size_t)N_NODES * 256 * es);
  ST* B3  = (ST*)alloc((size_t)N_NODES * 128 * es);
  ST* X2c = (ST*)alloc((size_t)CHUNK * 256 * es);

  hipMemsetAsync(degi, 0, (size_t)N_NODES * 4, stream);
  hipMemsetAsync(cursor, 0, (size_t)N_NODES * 4, stream);
  hipMemsetAsync(hg, 0, (size_t)N_GRAPH * 512 * 4, stream);

  k_deg<<<(N_EDGES + 255) / 256, 256, 0, stream>>>(dst, degi);
  k_norm<<<(N_NODES + 255) / 256, 256, 0, stream>>>(degi, nrm);
  k_scan<<<1, 1024, 0, stream>>>(degi, rowptr);
  k_scatter<<<(N_EDGES + 255) / 256, 256, 0, stream>>>(src, dst, rowptr, cursor, colidx);

  auto ahat = [&](const ST* hin, const ST* hadd, ST* outb, int F, int base, int nr,
                  float alpha, float beta) {
    dim3 g((nr + 3) / 4);  // 4 waves per 256-thread block, one wave per node
    if (F == 128) k_ahat<ST, 2><<<g, 256, 0, stream>>>(hin, hadd, nrm, rowptr, colidx, outb, F, base, nr, alpha, beta);
    else          k_ahat<ST, 4><<<g, 256, 0, stream>>>(hin, hadd, nrm, rowptr, colidx, outb, F, base, nr, alpha, beta);
  };

  auto layer = [&](const ST* hin, int F, const float* W, const float* bias,
                   ST* X1, ST* hout, int fout, bool pool) {
    ahat(hin, nullptr, X1, F, 0, N_NODES, -1.f, 0.f);           // X1 = -Ahat x0  (full)
    for (int base = 0; base < N_NODES; base += CHUNK) {
      int nr = (N_NODES - base < CHUNK) ? (N_NODES - base) : CHUNK;
      // X2c = -2 Ahat X1 - X0   (chunk rows)
      ahat(X1, hin + (size_t)base * F, X2c, F, base, nr, -2.f, -1.f);
      dim3 gg((nr + 63) / 64, fout / 64);
      if (pool)
        k_gemm3_relu<ST, true><<<gg, 256, 0, stream>>>(
            hin + (size_t)base * F, X1 + (size_t)base * F, X2c, F, W, bias,
            (ST*)nullptr, hg, gid + base, fout, nr);
      else
        k_gemm3_relu<ST, false><<<gg, 256, 0, stream>>>(
            hin + (size_t)base * F, X1 + (size_t)base * F, X2c, F, W, bias,
            hout + (size_t)base * fout, nullptr, nullptr, fout, nr);
    }
  };

  // Layer inputs: L1 signal(->B1 if bf16), L2 B2, L3 B1, L4 B2. X1: B3,B3,B3,B1.
  const ST* in0;
  if constexpr (std::is_same_v<ST, float>) {
    in0 = (const ST*)signal;
  } else {
    k_cast<<<(N_NODES * 128 + 255) / 256, 256, 0, stream>>>(signal, (unsigned short*)B1, N_NODES * 128);
    in0 = B1;
  }
  layer(in0, 128, W0, b0, B3, B2, 128, false);
  layer(B2,  128, W1, b1, B3, B1, 128, false);
  layer(B1,  128, W2, b2, B3, B2, 256, false);
  layer(B2,  256, W3, b3, B1, nullptr, 512, true);

  k_mlp<<<N_GRAPH, 512, 0, stream>>>(hg, Wm1, bm1, Wm2, bm2, outp);
}

// ---------------- launch ----------------
extern "C" void kernel_launch(void* const* d_in, const int* in_sizes, int n_in,
                              void* d_out, int out_size, void* d_ws, size_t ws_size,
                              hipStream_t stream) {
  (void)in_sizes; (void)n_in; (void)out_size;
  // f32 path needs ~290 MB of workspace; bf16 fallback ~149 MB.
  if (ws_size >= (size_t)292 * 1000 * 1000)
    run_pipeline<float>(d_in, (float*)d_out, (char*)d_ws, stream);
  else
    run_pipeline<unsigned short>(d_in, (float*)d_out, (char*)d_ws, stream);
}

// Round 4
// 2753.725 us; speedup vs baseline: 2.2872x; 2.2872x over previous
//
#include <hip/hip_runtime.h>
#include <hip/hip_bf16.h>

#define N_NODES 100000
#define PAD_N   100096   // multiple of 128
#define N_EDGES 1600000
#define N_GRAPH 128

typedef unsigned short u16;
typedef __attribute__((ext_vector_type(4))) float f32x4;
typedef __attribute__((ext_vector_type(8))) short s16x8;

__device__ __forceinline__ float bf2f(u16 u) {
  unsigned int v = ((unsigned int)u) << 16;
  float f; __builtin_memcpy(&f, &v, 4); return f;
}
__device__ __forceinline__ u16 f2bf(float f) {
  unsigned int v; __builtin_memcpy(&v, &f, 4);
  return (u16)((v + 0x7FFFu + ((v >> 16) & 1u)) >> 16);
}
__device__ __forceinline__ void split2(float v, u16& h, u16& l) {
  h = f2bf(v);
  l = f2bf(v - bf2f(h));
}
__device__ __forceinline__ void glds16(const u16* g, u16* l) {
  __builtin_amdgcn_global_load_lds(
      (const __attribute__((address_space(1))) unsigned int*)g,
      (__attribute__((address_space(3))) unsigned int*)l, 16, 0, 0);
}

// ---------------- graph preprocessing ----------------
__global__ void k_deg(const int* __restrict__ dst, int* __restrict__ degi) {
  int e = blockIdx.x * 256 + threadIdx.x;
  if (e < N_EDGES) atomicAdd(&degi[dst[e]], 1);
}

__global__ void k_norm(const int* __restrict__ degi, float* __restrict__ nrm) {
  int i = blockIdx.x * 256 + threadIdx.x;
  if (i < N_NODES) {
    int d = degi[i]; if (d < 1) d = 1;
    nrm[i] = 1.0f / sqrtf((float)d);
  }
}

__global__ void k_scan(const int* __restrict__ degi, int* __restrict__ rowptr) {
  __shared__ int sm[1024];
  __shared__ int carry_s;
  if (threadIdx.x == 0) carry_s = 0;
  __syncthreads();
  for (int base = 0; base < N_NODES; base += 1024) {
    int c = carry_s;
    int i = base + threadIdx.x;
    int v = (i < N_NODES) ? degi[i] : 0;
    sm[threadIdx.x] = v;
    __syncthreads();
    for (int off = 1; off < 1024; off <<= 1) {
      int t = (threadIdx.x >= off) ? sm[threadIdx.x - off] : 0;
      __syncthreads();
      sm[threadIdx.x] += t;
      __syncthreads();
    }
    if (i < N_NODES) rowptr[i] = c + sm[threadIdx.x] - v;  // exclusive
    int tot = sm[1023];
    __syncthreads();
    if (threadIdx.x == 0) carry_s = c + tot;
    __syncthreads();
  }
  if (threadIdx.x == 0) rowptr[N_NODES] = carry_s;
}

__global__ void k_scatter(const int* __restrict__ src, const int* __restrict__ dst,
                          const int* __restrict__ rowptr, int* __restrict__ cursor,
                          int* __restrict__ colidx) {
  int e = blockIdx.x * 256 + threadIdx.x;
  if (e >= N_EDGES) return;
  int d = dst[e];
  int p = atomicAdd(&cursor[d], 1);
  colidx[rowptr[d] + p] = src[e];
}

// ---------------- split/cast kernels ----------------
// W [K3][fout] f32 -> Wt_hi/Wt_lo [fout][K3] bf16 (split keeps weights ~exact)
__global__ void k_wsplit(const float* __restrict__ W, u16* __restrict__ th,
                         u16* __restrict__ tl, int K3, int fout) {
  int i = blockIdx.x * 256 + threadIdx.x;
  if (i >= K3 * fout) return;
  int k = i / fout, n = i % fout;
  u16 h, l; split2(W[i], h, l);
  th[(size_t)n * K3 + k] = h;
  tl[(size_t)n * K3 + k] = l;
}

__global__ void k_sigcast(const float* __restrict__ s, u16* __restrict__ h) {
  int i = blockIdx.x * 256 + threadIdx.x;
  if (i >= PAD_N * 128) return;
  float v = (i < N_NODES * 128) ? s[i] : 0.f;
  h[i] = f2bf(v);
}

// ---------------- Ahat aggregation (bf16 storage, f32 math) ----------------
// out[nl] = alpha*nrm[node]*sum_{s in nbr(node)} hin[s]*nrm[s] + beta*hadd[nl]
template<int VEC>
__global__ void k_ahat_bf(const u16* __restrict__ gh, const u16* __restrict__ adh,
                          const float* __restrict__ nrm, const int* __restrict__ rowptr,
                          const int* __restrict__ colidx, u16* __restrict__ oh,
                          int F, int base, int nrows, float alpha, float beta) {
  int nl = (blockIdx.x * blockDim.x + threadIdx.x) >> 6;
  int lane = threadIdx.x & 63;
  if (nl >= nrows) return;
  int node = base + nl;
  int fo = lane * VEC;
  float res[VEC];
  if (node < N_NODES) {
    float acc[VEC];
#pragma unroll
    for (int v = 0; v < VEC; ++v) acc[v] = 0.f;
    int e0 = rowptr[node], e1 = rowptr[node + 1];
    for (int e = e0; e < e1; ++e) {
      int s = colidx[e];
      float ns = nrm[s];
      const u16* ph = gh + (size_t)s * F + fo;
      if constexpr (VEC == 2) {
        unsigned int uh = *(const unsigned int*)ph;
        acc[0] += bf2f((u16)uh) * ns;
        acc[1] += bf2f((u16)(uh >> 16)) * ns;
      } else {
        uint2 uh = *(const uint2*)ph;
        acc[0] += bf2f((u16)uh.x) * ns;
        acc[1] += bf2f((u16)(uh.x >> 16)) * ns;
        acc[2] += bf2f((u16)uh.y) * ns;
        acc[3] += bf2f((u16)(uh.y >> 16)) * ns;
      }
    }
    float sc = alpha * nrm[node];
    if (adh != nullptr) {
      const u16* pa = adh + (size_t)nl * F + fo;
      if constexpr (VEC == 2) {
        unsigned int ua = *(const unsigned int*)pa;
        res[0] = sc * acc[0] + beta * bf2f((u16)ua);
        res[1] = sc * acc[1] + beta * bf2f((u16)(ua >> 16));
      } else {
        uint2 ua = *(const uint2*)pa;
        res[0] = sc * acc[0] + beta * bf2f((u16)ua.x);
        res[1] = sc * acc[1] + beta * bf2f((u16)(ua.x >> 16));
        res[2] = sc * acc[2] + beta * bf2f((u16)ua.y);
        res[3] = sc * acc[3] + beta * bf2f((u16)(ua.y >> 16));
      }
    } else {
#pragma unroll
      for (int v = 0; v < VEC; ++v) res[v] = sc * acc[v];
    }
  } else {
#pragma unroll
    for (int v = 0; v < VEC; ++v) res[v] = 0.f;
  }
  u16* po = oh + (size_t)nl * F + fo;
  if constexpr (VEC == 2) {
    *(unsigned int*)po = (unsigned int)f2bf(res[0]) | ((unsigned int)f2bf(res[1]) << 16);
  } else {
    uint2 w;
    w.x = (unsigned int)f2bf(res[0]) | ((unsigned int)f2bf(res[1]) << 16);
    w.y = (unsigned int)f2bf(res[2]) | ((unsigned int)f2bf(res[3]) << 16);
    *(uint2*)po = w;
  }
}

// ---------------- MFMA GEMM: relu([X0|X1|X2] @ W + b) ----------------
// A: bf16 row-major [rows][F]; B: split W^T planes [fout][K3].
// Tile 128x128, BK=32, 2x2 waves of 64x64. LDS [kgroup4][idx128][8] per tile.
template<bool POOL>
__launch_bounds__(256)
__global__ void k_gemm_mfma(const u16* __restrict__ A0, const u16* __restrict__ A1,
                            const u16* __restrict__ A2, int F,
                            const u16* __restrict__ Bth, const u16* __restrict__ Btl,
                            const float* __restrict__ bias, u16* __restrict__ O,
                            float* __restrict__ hg, const int* __restrict__ gid,
                            int fout, int nrows) {
  __shared__ u16 As [4][128][8];
  __shared__ u16 Bsh[4][128][8];
  __shared__ u16 Bsl[4][128][8];
  const int tid = threadIdx.x;
  const int lane = tid & 63, wid = tid >> 6;
  const int wm = wid >> 1, wn = wid & 1;
  const int row0 = blockIdx.x * 128, col0 = blockIdx.y * 128;
  const int K3 = 3 * F;
  const int li = lane & 15, kq = lane >> 4;
  f32x4 acc[4][4];
#pragma unroll
  for (int m = 0; m < 4; ++m)
#pragma unroll
    for (int n = 0; n < 4; ++n) acc[m][n] = (f32x4){0.f, 0.f, 0.f, 0.f};

  for (int k0 = 0; k0 < K3; k0 += 32) {
    const u16* S; int kk;
    if (k0 < F)          { S = A0; kk = k0; }
    else if (k0 < 2 * F) { S = A1; kk = k0 - F; }
    else                 { S = A2; kk = k0 - 2 * F; }
#pragma unroll
    for (int r = 0; r < 2; ++r) {
      int s = r * 256 + tid;
      int kg = s >> 7, idx = s & 127;
      size_t ga = (size_t)(row0 + idx) * F + (kk + kg * 8);
      size_t gb = (size_t)(col0 + idx) * K3 + (k0 + kg * 8);
      size_t dso = (size_t)(r * 256 + wid * 64) * 8;  // wave-uniform LDS base (u16 units)
      glds16(S + ga,   &As [0][0][0] + dso);
      glds16(Bth + gb, &Bsh[0][0][0] + dso);
      glds16(Btl + gb, &Bsl[0][0][0] + dso);
    }
    __syncthreads();   // compiler drains vmcnt before barrier -> tiles ready
    s16x8 a[4], bh[4], bl[4];
#pragma unroll
    for (int m = 0; m < 4; ++m)
      a[m] = *(const s16x8*)&As[kq][wm * 64 + m * 16 + li][0];
#pragma unroll
    for (int n = 0; n < 4; ++n) {
      int cc = wn * 64 + n * 16 + li;
      bh[n] = *(const s16x8*)&Bsh[kq][cc][0];
      bl[n] = *(const s16x8*)&Bsl[kq][cc][0];
    }
#pragma unroll
    for (int m = 0; m < 4; ++m)
#pragma unroll
      for (int n = 0; n < 4; ++n) {
        acc[m][n] = __builtin_amdgcn_mfma_f32_16x16x32_bf16(a[m], bh[n], acc[m][n], 0, 0, 0);
        acc[m][n] = __builtin_amdgcn_mfma_f32_16x16x32_bf16(a[m], bl[n], acc[m][n], 0, 0, 0);
      }
    __syncthreads();
  }

  if (!POOL) {
#pragma unroll
    for (int m = 0; m < 4; ++m) {
      int rbase = row0 + wm * 64 + m * 16 + kq * 4;
#pragma unroll
      for (int n = 0; n < 4; ++n) {
        int col = col0 + wn * 64 + n * 16 + li;
        float bi = bias[col];
#pragma unroll
        for (int r = 0; r < 4; ++r) {
          int rr = rbase + r;
          if (rr < nrows)
            O[(size_t)rr * fout + col] = f2bf(fmaxf(acc[m][n][r] + bi, 0.f));
        }
      }
    }
  } else {
#pragma unroll
    for (int m = 0; m < 4; ++m) {
      int rbase = row0 + wm * 64 + m * 16 + kq * 4;
      int g4[4];
#pragma unroll
      for (int r = 0; r < 4; ++r) {
        int rr = rbase + r;
        g4[r] = (rr < nrows) ? gid[rr] : -1;
      }
#pragma unroll
      for (int n = 0; n < 4; ++n) {
        int col = col0 + wn * 64 + n * 16 + li;
        float bi = bias[col];
        float sum = 0.f; int curg = g4[0];
#pragma unroll
        for (int r = 0; r < 4; ++r) {
          if (g4[r] != curg) {
            if (curg >= 0) atomicAdd(&hg[curg * 512 + col], sum);
            sum = 0.f; curg = g4[r];
          }
          if (g4[r] >= 0) sum += fmaxf(acc[m][n][r] + bi, 0.f);
        }
        if (curg >= 0) atomicAdd(&hg[curg * 512 + col], sum);
      }
    }
  }
}

// ---------------- MLP head ----------------
__global__ void k_mlp(const float* __restrict__ hg, const float* __restrict__ Wm1,
                      const float* __restrict__ bm1, const float* __restrict__ Wm2,
                      const float* __restrict__ bm2, float* __restrict__ outp) {
  __shared__ float lh[512];
  __shared__ float lt[512];
  int g = blockIdx.x, t = threadIdx.x;
  lh[t] = hg[g * 512 + t];
  __syncthreads();
  float s = bm1[t];
  for (int k = 0; k < 512; ++k) s += lh[k] * Wm1[k * 512 + t];
  lt[t] = fmaxf(s, 0.f);
  __syncthreads();
  if (t < 10) {
    float s2 = bm2[t];
    for (int j = 0; j < 512; ++j) s2 += lt[j] * Wm2[j * 10 + t];
    outp[g * 10 + t] = s2;
  }
}

// ---------------- launch ----------------
extern "C" void kernel_launch(void* const* d_in, const int* in_sizes, int n_in,
                              void* d_out, int out_size, void* d_ws, size_t ws_size,
                              hipStream_t stream) {
  (void)in_sizes; (void)n_in; (void)out_size; (void)ws_size;
  const float* signal = (const float*)d_in[0];
  const float* W0 = (const float*)d_in[1];  const float* b0 = (const float*)d_in[2];
  const float* W1 = (const float*)d_in[3];  const float* b1 = (const float*)d_in[4];
  const float* W2 = (const float*)d_in[5];  const float* b2 = (const float*)d_in[6];
  const float* W3 = (const float*)d_in[7];  const float* b3 = (const float*)d_in[8];
  const float* Wm1 = (const float*)d_in[9];  const float* bm1 = (const float*)d_in[10];
  const float* Wm2 = (const float*)d_in[11]; const float* bm2 = (const float*)d_in[12];
  const int* src = (const int*)d_in[13];
  const int* dst = (const int*)d_in[14];
  const int* gid = (const int*)d_in[15];
  float* outp = (float*)d_out;

  char* ws = (char*)d_ws;
  size_t off = 0;
  auto alloc = [&](size_t b) -> void* {
    void* p = ws + off;
    off = (off + b + 255) & ~(size_t)255;
    return p;
  };
  // total ws footprint ~145 MB (round-2 bf16 path proved >=149 MB is available)
  int* degi    = (int*)alloc((size_t)N_NODES * 4);
  float* nrm   = (float*)alloc((size_t)N_NODES * 4);
  int* rowptr  = (int*)alloc((size_t)(N_NODES + 1) * 4);
  int* cursor  = (int*)alloc((size_t)N_NODES * 4);
  int* colidx  = (int*)alloc((size_t)N_EDGES * 4);
  float* hg    = (float*)alloc((size_t)N_GRAPH * 512 * 4);
  u16* Wth0 = (u16*)alloc((size_t)384 * 128 * 2);
  u16* Wtl0 = (u16*)alloc((size_t)384 * 128 * 2);
  u16* Wth1 = (u16*)alloc((size_t)384 * 128 * 2);
  u16* Wtl1 = (u16*)alloc((size_t)384 * 128 * 2);
  u16* Wth2 = (u16*)alloc((size_t)384 * 256 * 2);
  u16* Wtl2 = (u16*)alloc((size_t)384 * 256 * 2);
  u16* Wth3 = (u16*)alloc((size_t)768 * 512 * 2);
  u16* Wtl3 = (u16*)alloc((size_t)768 * 512 * 2);
  u16* QA  = (u16*)alloc((size_t)PAD_N * 256 * 2);
  u16* QB  = (u16*)alloc((size_t)PAD_N * 128 * 2);
  u16* QX  = (u16*)alloc((size_t)PAD_N * 256 * 2);
  u16* X2c = (u16*)alloc((size_t)25088 * 128 * 2);   // == 12544*256

  hipMemsetAsync(degi, 0, (size_t)N_NODES * 4, stream);
  hipMemsetAsync(cursor, 0, (size_t)N_NODES * 4, stream);
  hipMemsetAsync(hg, 0, (size_t)N_GRAPH * 512 * 4, stream);

  k_deg<<<(N_EDGES + 255) / 256, 256, 0, stream>>>(dst, degi);
  k_norm<<<(N_NODES + 255) / 256, 256, 0, stream>>>(degi, nrm);
  k_scan<<<1, 1024, 0, stream>>>(degi, rowptr);
  k_scatter<<<(N_EDGES + 255) / 256, 256, 0, stream>>>(src, dst, rowptr, cursor, colidx);

  k_wsplit<<<(384 * 128 + 255) / 256, 256, 0, stream>>>(W0, Wth0, Wtl0, 384, 128);
  k_wsplit<<<(384 * 128 + 255) / 256, 256, 0, stream>>>(W1, Wth1, Wtl1, 384, 128);
  k_wsplit<<<(384 * 256 + 255) / 256, 256, 0, stream>>>(W2, Wth2, Wtl2, 384, 256);
  k_wsplit<<<(768 * 512 + 255) / 256, 256, 0, stream>>>(W3, Wth3, Wtl3, 768, 512);
  k_sigcast<<<(PAD_N * 128 + 255) / 256, 256, 0, stream>>>(signal, QB);

  auto layer = [&](const u16* in, int F, const u16* wth, const u16* wtl,
                   const float* bias, u16* outb, int fout, bool pool) {
    // X1 = -Ahat x0 over all padded rows (pad rows -> 0)
    int gfull = (PAD_N + 3) / 4;
    if (F == 128)
      k_ahat_bf<2><<<gfull, 256, 0, stream>>>(in, nullptr, nrm, rowptr, colidx,
                                              QX, F, 0, PAD_N, -1.f, 0.f);
    else
      k_ahat_bf<4><<<gfull, 256, 0, stream>>>(in, nullptr, nrm, rowptr, colidx,
                                              QX, F, 0, PAD_N, -1.f, 0.f);
    int CH = (F == 128) ? 25088 : 12544;
    for (int base = 0; base < N_NODES; base += CH) {
      int nr = (N_NODES - base < CH) ? (N_NODES - base) : CH;
      // X2c = -2 Ahat X1 - X0 (chunk rows)
      if (F == 128)
        k_ahat_bf<2><<<(nr + 3) / 4, 256, 0, stream>>>(QX, in + (size_t)base * F, nrm,
            rowptr, colidx, X2c, F, base, nr, -2.f, -1.f);
      else
        k_ahat_bf<4><<<(nr + 3) / 4, 256, 0, stream>>>(QX, in + (size_t)base * F, nrm,
            rowptr, colidx, X2c, F, base, nr, -2.f, -1.f);
      dim3 gg((nr + 127) / 128, fout / 128);
      if (pool)
        k_gemm_mfma<true><<<gg, 256, 0, stream>>>(
            in + (size_t)base * F, QX + (size_t)base * F, X2c, F,
            wth, wtl, bias, nullptr, hg, gid + base, fout, nr);
      else
        k_gemm_mfma<false><<<gg, 256, 0, stream>>>(
            in + (size_t)base * F, QX + (size_t)base * F, X2c, F,
            wth, wtl, bias, outb + (size_t)base * fout, nullptr, nullptr, fout, nr);
    }
  };

  layer(QB, 128, Wth0, Wtl0, b0, QA, 128, false);
  layer(QA, 128, Wth1, Wtl1, b1, QB, 128, false);
  layer(QB, 128, Wth2, Wtl2, b2, QA, 256, false);
  layer(QA, 256, Wth3, Wtl3, b3, nullptr, 512, true);

  k_mlp<<<N_GRAPH, 512, 0, stream>>>(hg, Wm1, bm1, Wm2, bm2, outp);
}

// Round 5
// 2364.480 us; speedup vs baseline: 2.6638x; 1.1646x over previous
//
#include <hip/hip_runtime.h>
#include <hip/hip_bf16.h>

#define N_NODES 100000
#define PAD_N   100096   // multiple of 128
#define N_EDGES 1600000
#define N_GRAPH 128
#define SCAN_B  1024
#define SCAN_G  ((N_NODES + SCAN_B - 1) / SCAN_B)   // 98

typedef unsigned short u16;
typedef __attribute__((ext_vector_type(4))) float f32x4;
typedef __attribute__((ext_vector_type(8))) short s16x8;

__device__ __forceinline__ float bf2f(u16 u) {
  unsigned int v = ((unsigned int)u) << 16;
  float f; __builtin_memcpy(&f, &v, 4); return f;
}
__device__ __forceinline__ u16 f2bf(float f) {
  unsigned int v; __builtin_memcpy(&v, &f, 4);
  return (u16)((v + 0x7FFFu + ((v >> 16) & 1u)) >> 16);
}
__device__ __forceinline__ void split2(float v, u16& h, u16& l) {
  h = f2bf(v);
  l = f2bf(v - bf2f(h));
}
__device__ __forceinline__ void glds16(const u16* g, u16* l) {
  __builtin_amdgcn_global_load_lds(
      (const __attribute__((address_space(1))) unsigned int*)g,
      (__attribute__((address_space(3))) unsigned int*)l, 16, 0, 0);
}

// ---------------- graph preprocessing ----------------
__global__ void k_deg(const int* __restrict__ dst, int* __restrict__ degi) {
  int e = blockIdx.x * 256 + threadIdx.x;
  if (e < N_EDGES) atomicAdd(&degi[dst[e]], 1);
}

__global__ void k_norm(const int* __restrict__ degi, float* __restrict__ nrm) {
  int i = blockIdx.x * 256 + threadIdx.x;
  if (i < N_NODES) {
    int d = degi[i]; if (d < 1) d = 1;
    nrm[i] = 1.0f / sqrtf((float)d);
  }
}

// hierarchical exclusive scan: per-block scan -> scan block sums -> add offsets
__global__ void k_scan1(const int* __restrict__ degi, int* __restrict__ rowptr,
                        int* __restrict__ bsum) {
  __shared__ int sm[SCAN_B];
  int i = blockIdx.x * SCAN_B + threadIdx.x;
  int v = (i < N_NODES) ? degi[i] : 0;
  sm[threadIdx.x] = v;
  __syncthreads();
  for (int off = 1; off < SCAN_B; off <<= 1) {
    int t = (threadIdx.x >= off) ? sm[threadIdx.x - off] : 0;
    __syncthreads();
    sm[threadIdx.x] += t;
    __syncthreads();
  }
  if (i < N_NODES) rowptr[i] = sm[threadIdx.x] - v;   // block-local exclusive
  if (threadIdx.x == SCAN_B - 1) bsum[blockIdx.x] = sm[SCAN_B - 1];
}

__global__ void k_scan2(const int* __restrict__ bsum, int* __restrict__ boff,
                        int* __restrict__ rowptr) {
  __shared__ int sm[128];
  int v = (threadIdx.x < SCAN_G) ? bsum[threadIdx.x] : 0;
  sm[threadIdx.x] = v;
  __syncthreads();
  for (int off = 1; off < 128; off <<= 1) {
    int t = (threadIdx.x >= off) ? sm[threadIdx.x - off] : 0;
    __syncthreads();
    sm[threadIdx.x] += t;
    __syncthreads();
  }
  if (threadIdx.x < SCAN_G) boff[threadIdx.x] = sm[threadIdx.x] - v;
  if (threadIdx.x == 127) rowptr[N_NODES] = sm[127];
}

__global__ void k_scan3(int* __restrict__ rowptr, const int* __restrict__ boff) {
  int i = blockIdx.x * SCAN_B + threadIdx.x;
  if (i < N_NODES) rowptr[i] += boff[blockIdx.x];
}

__global__ void k_scatter(const int* __restrict__ src, const int* __restrict__ dst,
                          const int* __restrict__ rowptr, int* __restrict__ cursor,
                          int* __restrict__ colidx) {
  int e = blockIdx.x * 256 + threadIdx.x;
  if (e >= N_EDGES) return;
  int d = dst[e];
  int p = atomicAdd(&cursor[d], 1);
  colidx[rowptr[d] + p] = src[e];
}

// ---------------- weight transform + split ----------------
// Logical weights for GEMM over [X0 | X1 | Y=Ahat X1]:
//   rows [0,F)    : Wa - Wc
//   rows [F,2F)   : Wb
//   rows [2F,3F)  : -2*Wc
// stored transposed [fout][K3] as hi/lo bf16 planes.
__global__ void k_wsplit(const float* __restrict__ W, u16* __restrict__ th,
                         u16* __restrict__ tl, int F, int fout) {
  int K3 = 3 * F;
  int i = blockIdx.x * 256 + threadIdx.x;
  if (i >= K3 * fout) return;
  int k = i / fout, n = i % fout;
  float v;
  if (k < F)          v = W[(size_t)k * fout + n] - W[(size_t)(k + 2 * F) * fout + n];
  else if (k < 2 * F) v = W[(size_t)k * fout + n];
  else                v = -2.0f * W[(size_t)k * fout + n];
  u16 h, l; split2(v, h, l);
  th[(size_t)n * K3 + k] = h;
  tl[(size_t)n * K3 + k] = l;
}

__global__ void k_sigcast(const float* __restrict__ s, u16* __restrict__ h) {
  int i = blockIdx.x * 256 + threadIdx.x;
  if (i >= PAD_N * 128) return;
  float v = (i < N_NODES * 128) ? s[i] : 0.f;
  h[i] = f2bf(v);
}

// ---------------- Ahat aggregation (bf16 storage, f32 math) ----------------
// out[nl] = alpha * nrm[node] * sum_{s in nbr(node)} hin[s]*nrm[s];  node = base+nl
template<int VEC>
__global__ void k_ahat_bf(const u16* __restrict__ gh, const float* __restrict__ nrm,
                          const int* __restrict__ rowptr, const int* __restrict__ colidx,
                          u16* __restrict__ oh, int F, int base, int nrows, float alpha) {
  int nl = (blockIdx.x * blockDim.x + threadIdx.x) >> 6;
  int lane = threadIdx.x & 63;
  if (nl >= nrows) return;
  int node = base + nl;
  int fo = lane * VEC;
  float res[VEC];
  if (node < N_NODES) {
    float acc[VEC];
#pragma unroll
    for (int v = 0; v < VEC; ++v) acc[v] = 0.f;
    int e0 = rowptr[node], e1 = rowptr[node + 1];
    for (int e = e0; e < e1; ++e) {
      int s = colidx[e];
      float ns = nrm[s];
      const u16* ph = gh + (size_t)s * F + fo;
      if constexpr (VEC == 2) {
        unsigned int uh = *(const unsigned int*)ph;
        acc[0] += bf2f((u16)uh) * ns;
        acc[1] += bf2f((u16)(uh >> 16)) * ns;
      } else {
        uint2 uh = *(const uint2*)ph;
        acc[0] += bf2f((u16)uh.x) * ns;
        acc[1] += bf2f((u16)(uh.x >> 16)) * ns;
        acc[2] += bf2f((u16)uh.y) * ns;
        acc[3] += bf2f((u16)(uh.y >> 16)) * ns;
      }
    }
    float sc = alpha * nrm[node];
#pragma unroll
    for (int v = 0; v < VEC; ++v) res[v] = sc * acc[v];
  } else {
#pragma unroll
    for (int v = 0; v < VEC; ++v) res[v] = 0.f;
  }
  u16* po = oh + (size_t)nl * F + fo;
  if constexpr (VEC == 2) {
    *(unsigned int*)po = (unsigned int)f2bf(res[0]) | ((unsigned int)f2bf(res[1]) << 16);
  } else {
    uint2 w;
    w.x = (unsigned int)f2bf(res[0]) | ((unsigned int)f2bf(res[1]) << 16);
    w.y = (unsigned int)f2bf(res[2]) | ((unsigned int)f2bf(res[3]) << 16);
    *(uint2*)po = w;
  }
}

// ---------------- MFMA GEMM: relu([X0|X1|Y] @ W' + b) ----------------
// A: bf16 row-major [rows][F]; B: split W'^T planes [fout][K3].
// Tile 128x128, BK=32, 2x2 waves of 64x64. LDS [kgroup4][idx128][8] per tile.
template<bool POOL>
__launch_bounds__(256)
__global__ void k_gemm_mfma(const u16* __restrict__ A0, const u16* __restrict__ A1,
                            const u16* __restrict__ A2, int F,
                            const u16* __restrict__ Bth, const u16* __restrict__ Btl,
                            const float* __restrict__ bias, u16* __restrict__ O,
                            float* __restrict__ hg, const int* __restrict__ gid,
                            int fout, int nrows) {
  __shared__ u16 As [4][128][8];
  __shared__ u16 Bsh[4][128][8];
  __shared__ u16 Bsl[4][128][8];
  const int tid = threadIdx.x;
  const int lane = tid & 63, wid = tid >> 6;
  const int wm = wid >> 1, wn = wid & 1;
  const int row0 = blockIdx.x * 128, col0 = blockIdx.y * 128;
  const int K3 = 3 * F;
  const int li = lane & 15, kq = lane >> 4;
  f32x4 acc[4][4];
#pragma unroll
  for (int m = 0; m < 4; ++m)
#pragma unroll
    for (int n = 0; n < 4; ++n) acc[m][n] = (f32x4){0.f, 0.f, 0.f, 0.f};

  for (int k0 = 0; k0 < K3; k0 += 32) {
    const u16* S; int kk;
    if (k0 < F)          { S = A0; kk = k0; }
    else if (k0 < 2 * F) { S = A1; kk = k0 - F; }
    else                 { S = A2; kk = k0 - 2 * F; }
#pragma unroll
    for (int r = 0; r < 2; ++r) {
      int s = r * 256 + tid;
      int kg = s >> 7, idx = s & 127;
      size_t ga = (size_t)(row0 + idx) * F + (kk + kg * 8);
      size_t gb = (size_t)(col0 + idx) * K3 + (k0 + kg * 8);
      size_t dso = (size_t)(r * 256 + wid * 64) * 8;  // wave-uniform LDS base (u16 units)
      glds16(S + ga,   &As [0][0][0] + dso);
      glds16(Bth + gb, &Bsh[0][0][0] + dso);
      glds16(Btl + gb, &Bsl[0][0][0] + dso);
    }
    __syncthreads();
    s16x8 a[4], bh[4], bl[4];
#pragma unroll
    for (int m = 0; m < 4; ++m)
      a[m] = *(const s16x8*)&As[kq][wm * 64 + m * 16 + li][0];
#pragma unroll
    for (int n = 0; n < 4; ++n) {
      int cc = wn * 64 + n * 16 + li;
      bh[n] = *(const s16x8*)&Bsh[kq][cc][0];
      bl[n] = *(const s16x8*)&Bsl[kq][cc][0];
    }
#pragma unroll
    for (int m = 0; m < 4; ++m)
#pragma unroll
      for (int n = 0; n < 4; ++n) {
        acc[m][n] = __builtin_amdgcn_mfma_f32_16x16x32_bf16(a[m], bh[n], acc[m][n], 0, 0, 0);
        acc[m][n] = __builtin_amdgcn_mfma_f32_16x16x32_bf16(a[m], bl[n], acc[m][n], 0, 0, 0);
      }
    __syncthreads();
  }

  if (!POOL) {
#pragma unroll
    for (int m = 0; m < 4; ++m) {
      int rbase = row0 + wm * 64 + m * 16 + kq * 4;
#pragma unroll
      for (int n = 0; n < 4; ++n) {
        int col = col0 + wn * 64 + n * 16 + li;
        float bi = bias[col];
#pragma unroll
        for (int r = 0; r < 4; ++r) {
          int rr = rbase + r;
          if (rr < nrows)
            O[(size_t)rr * fout + col] = f2bf(fmaxf(acc[m][n][r] + bi, 0.f));
        }
      }
    }
  } else {
#pragma unroll
    for (int m = 0; m < 4; ++m) {
      int rbase = row0 + wm * 64 + m * 16 + kq * 4;
      int g4[4];
#pragma unroll
      for (int r = 0; r < 4; ++r) {
        int rr = rbase + r;
        g4[r] = (rr < nrows) ? gid[rr] : -1;
      }
#pragma unroll
      for (int n = 0; n < 4; ++n) {
        int col = col0 + wn * 64 + n * 16 + li;
        float bi = bias[col];
        float sum = 0.f; int curg = g4[0];
#pragma unroll
        for (int r = 0; r < 4; ++r) {
          if (g4[r] != curg) {
            if (curg >= 0) atomicAdd(&hg[curg * 512 + col], sum);
            sum = 0.f; curg = g4[r];
          }
          if (g4[r] >= 0) sum += fmaxf(acc[m][n][r] + bi, 0.f);
        }
        if (curg >= 0) atomicAdd(&hg[curg * 512 + col], sum);
      }
    }
  }
}

// ---------------- MLP head ----------------
__global__ void k_mlp(const float* __restrict__ hg, const float* __restrict__ Wm1,
                      const float* __restrict__ bm1, const float* __restrict__ Wm2,
                      const float* __restrict__ bm2, float* __restrict__ outp) {
  __shared__ float lh[512];
  __shared__ float lt[512];
  int g = blockIdx.x, t = threadIdx.x;
  lh[t] = hg[g * 512 + t];
  __syncthreads();
  float s = bm1[t];
  for (int k = 0; k < 512; ++k) s += lh[k] * Wm1[k * 512 + t];
  lt[t] = fmaxf(s, 0.f);
  __syncthreads();
  if (t < 10) {
    float s2 = bm2[t];
    for (int j = 0; j < 512; ++j) s2 += lt[j] * Wm2[j * 10 + t];
    outp[g * 10 + t] = s2;
  }
}

// ---------------- launch ----------------
extern "C" void kernel_launch(void* const* d_in, const int* in_sizes, int n_in,
                              void* d_out, int out_size, void* d_ws, size_t ws_size,
                              hipStream_t stream) {
  (void)in_sizes; (void)n_in; (void)out_size; (void)ws_size;
  const float* signal = (const float*)d_in[0];
  const float* W0 = (const float*)d_in[1];  const float* b0 = (const float*)d_in[2];
  const float* W1 = (const float*)d_in[3];  const float* b1 = (const float*)d_in[4];
  const float* W2 = (const float*)d_in[5];  const float* b2 = (const float*)d_in[6];
  const float* W3 = (const float*)d_in[7];  const float* b3 = (const float*)d_in[8];
  const float* Wm1 = (const float*)d_in[9];  const float* bm1 = (const float*)d_in[10];
  const float* Wm2 = (const float*)d_in[11]; const float* bm2 = (const float*)d_in[12];
  const int* src = (const int*)d_in[13];
  const int* dst = (const int*)d_in[14];
  const int* gid = (const int*)d_in[15];
  float* outp = (float*)d_out;

  char* ws = (char*)d_ws;
  size_t off = 0;
  auto alloc = [&](size_t b) -> void* {
    void* p = ws + off;
    off = (off + b + 255) & ~(size_t)255;
    return p;
  };
  // total ws footprint ~139 MB (< 145 MB proven safe in round 4)
  int* degi    = (int*)alloc((size_t)N_NODES * 4);
  float* nrm   = (float*)alloc((size_t)N_NODES * 4);
  int* rowptr  = (int*)alloc((size_t)(N_NODES + 1) * 4);
  int* cursor  = (int*)alloc((size_t)N_NODES * 4);
  int* bsum    = (int*)alloc((size_t)SCAN_G * 4);
  int* boff    = (int*)alloc((size_t)SCAN_G * 4);
  int* colidx  = (int*)alloc((size_t)N_EDGES * 4);
  float* hg    = (float*)alloc((size_t)N_GRAPH * 512 * 4);
  u16* Wth0 = (u16*)alloc((size_t)384 * 128 * 2);
  u16* Wtl0 = (u16*)alloc((size_t)384 * 128 * 2);
  u16* Wth1 = (u16*)alloc((size_t)384 * 128 * 2);
  u16* Wtl1 = (u16*)alloc((size_t)384 * 128 * 2);
  u16* Wth2 = (u16*)alloc((size_t)384 * 256 * 2);
  u16* Wtl2 = (u16*)alloc((size_t)384 * 256 * 2);
  u16* Wth3 = (u16*)alloc((size_t)768 * 512 * 2);
  u16* Wtl3 = (u16*)alloc((size_t)768 * 512 * 2);
  u16* QA = (u16*)alloc((size_t)PAD_N * 256 * 2);   // L1 out / L2 in / L3 out / L4 in
  u16* QB = (u16*)alloc((size_t)PAD_N * 128 * 2);   // sig / L2 out / L3 in / L4 Y-chunk
  u16* QX = (u16*)alloc((size_t)PAD_N * 256 * 2);   // X1 (+Y in 2nd half for F=128)

  hipMemsetAsync(degi, 0, (size_t)N_NODES * 4, stream);
  hipMemsetAsync(cursor, 0, (size_t)N_NODES * 4, stream);
  hipMemsetAsync(hg, 0, (size_t)N_GRAPH * 512 * 4, stream);

  k_deg<<<(N_EDGES + 255) / 256, 256, 0, stream>>>(dst, degi);
  k_norm<<<(N_NODES + 255) / 256, 256, 0, stream>>>(degi, nrm);
  k_scan1<<<SCAN_G, SCAN_B, 0, stream>>>(degi, rowptr, bsum);
  k_scan2<<<1, 128, 0, stream>>>(bsum, boff, rowptr);
  k_scan3<<<SCAN_G, SCAN_B, 0, stream>>>(rowptr, boff);
  k_scatter<<<(N_EDGES + 255) / 256, 256, 0, stream>>>(src, dst, rowptr, cursor, colidx);

  k_wsplit<<<(384 * 128 + 255) / 256, 256, 0, stream>>>(W0, Wth0, Wtl0, 128, 128);
  k_wsplit<<<(384 * 128 + 255) / 256, 256, 0, stream>>>(W1, Wth1, Wtl1, 128, 128);
  k_wsplit<<<(384 * 256 + 255) / 256, 256, 0, stream>>>(W2, Wth2, Wtl2, 128, 256);
  k_wsplit<<<(768 * 512 + 255) / 256, 256, 0, stream>>>(W3, Wth3, Wtl3, 256, 512);
  k_sigcast<<<(PAD_N * 128 + 255) / 256, 256, 0, stream>>>(signal, QB);

  const int gfull = (PAD_N + 3) / 4;   // ahat grid, 4 nodes per 256-thread block

  // ---- layers 1-3 (F=128): X1 = QX half0, Y = QX half1, unchunked ----
  u16* X1h = QX;
  u16* Yh  = QX + (size_t)PAD_N * 128;
  auto layer128 = [&](const u16* in, const u16* wth, const u16* wtl,
                      const float* bias, u16* outb, int fout) {
    k_ahat_bf<2><<<gfull, 256, 0, stream>>>(in,  nrm, rowptr, colidx, X1h, 128, 0, PAD_N, -1.f);
    k_ahat_bf<2><<<gfull, 256, 0, stream>>>(X1h, nrm, rowptr, colidx, Yh,  128, 0, PAD_N,  1.f);
    dim3 gg(PAD_N / 128, fout / 128);
    k_gemm_mfma<false><<<gg, 256, 0, stream>>>(in, X1h, Yh, 128, wth, wtl, bias,
                                               outb, nullptr, nullptr, fout, N_NODES);
  };
  layer128(QB, Wth0, Wtl0, b0, QA, 128);
  layer128(QA, Wth1, Wtl1, b1, QB, 128);
  layer128(QB, Wth2, Wtl2, b2, QA, 256);

  // ---- layer 4 (F=256, fout=512, pooled): X1 = QX full; Y chunks in QB ----
  k_ahat_bf<4><<<gfull, 256, 0, stream>>>(QA, nrm, rowptr, colidx, QX, 256, 0, PAD_N, -1.f);
  const int CH4 = 50048;   // CH4*256*2 bytes == QB capacity; multiple of 128
  for (int base = 0; base < N_NODES; base += CH4) {
    int nr = (N_NODES - base < CH4) ? (N_NODES - base) : CH4;
    k_ahat_bf<4><<<(nr + 3) / 4, 256, 0, stream>>>(QX, nrm, rowptr, colidx, QB,
                                                   256, base, nr, 1.f);
    dim3 gg((nr + 127) / 128, 4);
    k_gemm_mfma<true><<<gg, 256, 0, stream>>>(
        QA + (size_t)base * 256, QX + (size_t)base * 256, QB, 256,
        Wth3, Wtl3, b3, nullptr, hg, gid + base, 512, nr);
  }

  k_mlp<<<N_GRAPH, 512, 0, stream>>>(hg, Wm1, bm1, Wm2, bm2, outp);
}

// Round 6
// 2354.590 us; speedup vs baseline: 2.6749x; 1.0042x over previous
//
#include <hip/hip_runtime.h>
#include <hip/hip_bf16.h>

#define N_NODES 100000
#define PAD_N   100096   // multiple of 128
#define N_EDGES 1600000
#define N_GRAPH 128
#define SCAN_B  1024
#define SCAN_G  ((N_NODES + SCAN_B - 1) / SCAN_B)   // 98

typedef unsigned short u16;
typedef __attribute__((ext_vector_type(4))) float f32x4;
typedef __attribute__((ext_vector_type(8))) short s16x8;

__device__ __forceinline__ float bf2f(u16 u) {
  unsigned int v = ((unsigned int)u) << 16;
  float f; __builtin_memcpy(&f, &v, 4); return f;
}
__device__ __forceinline__ u16 f2bf(float f) {
  unsigned int v; __builtin_memcpy(&v, &f, 4);
  return (u16)((v + 0x7FFFu + ((v >> 16) & 1u)) >> 16);
}
__device__ __forceinline__ void split2(float v, u16& h, u16& l) {
  h = f2bf(v);
  l = f2bf(v - bf2f(h));
}
__device__ __forceinline__ void glds16(const u16* g, u16* l) {
  __builtin_amdgcn_global_load_lds(
      (const __attribute__((address_space(1))) unsigned int*)g,
      (__attribute__((address_space(3))) unsigned int*)l, 16, 0, 0);
}

// ---------------- graph preprocessing ----------------
__global__ void k_deg(const int* __restrict__ dst, int* __restrict__ degi) {
  int e = blockIdx.x * 256 + threadIdx.x;
  if (e < N_EDGES) atomicAdd(&degi[dst[e]], 1);
}

__global__ void k_norm(const int* __restrict__ degi, float* __restrict__ nrm) {
  int i = blockIdx.x * 256 + threadIdx.x;
  if (i < N_NODES) {
    int d = degi[i]; if (d < 1) d = 1;
    nrm[i] = 1.0f / sqrtf((float)d);
  }
}

// hierarchical exclusive scan: per-block scan -> scan block sums -> add offsets
__global__ void k_scan1(const int* __restrict__ degi, int* __restrict__ rowptr,
                        int* __restrict__ bsum) {
  __shared__ int sm[SCAN_B];
  int i = blockIdx.x * SCAN_B + threadIdx.x;
  int v = (i < N_NODES) ? degi[i] : 0;
  sm[threadIdx.x] = v;
  __syncthreads();
  for (int off = 1; off < SCAN_B; off <<= 1) {
    int t = (threadIdx.x >= off) ? sm[threadIdx.x - off] : 0;
    __syncthreads();
    sm[threadIdx.x] += t;
    __syncthreads();
  }
  if (i < N_NODES) rowptr[i] = sm[threadIdx.x] - v;   // block-local exclusive
  if (threadIdx.x == SCAN_B - 1) bsum[blockIdx.x] = sm[SCAN_B - 1];
}

__global__ void k_scan2(const int* __restrict__ bsum, int* __restrict__ boff,
                        int* __restrict__ rowptr) {
  __shared__ int sm[128];
  int v = (threadIdx.x < SCAN_G) ? bsum[threadIdx.x] : 0;
  sm[threadIdx.x] = v;
  __syncthreads();
  for (int off = 1; off < 128; off <<= 1) {
    int t = (threadIdx.x >= off) ? sm[threadIdx.x - off] : 0;
    __syncthreads();
    sm[threadIdx.x] += t;
    __syncthreads();
  }
  if (threadIdx.x < SCAN_G) boff[threadIdx.x] = sm[threadIdx.x] - v;
  if (threadIdx.x == 127) rowptr[N_NODES] = sm[127];
}

__global__ void k_scan3(int* __restrict__ rowptr, const int* __restrict__ boff) {
  int i = blockIdx.x * SCAN_B + threadIdx.x;
  if (i < N_NODES) rowptr[i] += boff[blockIdx.x];
}

__global__ void k_scatter(const int* __restrict__ src, const int* __restrict__ dst,
                          const int* __restrict__ rowptr, int* __restrict__ cursor,
                          int* __restrict__ colidx) {
  int e = blockIdx.x * 256 + threadIdx.x;
  if (e >= N_EDGES) return;
  int d = dst[e];
  int p = atomicAdd(&cursor[d], 1);
  colidx[rowptr[d] + p] = src[e];
}

// ---------------- weight transform + split ----------------
// Logical weights for GEMM over [X0 | X1 | Y=Ahat X1]:
//   rows [0,F): Wa - Wc ; rows [F,2F): Wb ; rows [2F,3F): -2*Wc
// stored transposed [fout][K3] as hi/lo bf16 planes.
__global__ void k_wsplit(const float* __restrict__ W, u16* __restrict__ th,
                         u16* __restrict__ tl, int F, int fout) {
  int K3 = 3 * F;
  int i = blockIdx.x * 256 + threadIdx.x;
  if (i >= K3 * fout) return;
  int k = i / fout, n = i % fout;
  float v;
  if (k < F)          v = W[(size_t)k * fout + n] - W[(size_t)(k + 2 * F) * fout + n];
  else if (k < 2 * F) v = W[(size_t)k * fout + n];
  else                v = -2.0f * W[(size_t)k * fout + n];
  u16 h, l; split2(v, h, l);
  th[(size_t)n * K3 + k] = h;
  tl[(size_t)n * K3 + k] = l;
}

__global__ void k_sigcast(const float* __restrict__ s, u16* __restrict__ h) {
  int i = blockIdx.x * 256 + threadIdx.x;
  if (i >= PAD_N * 128) return;
  float v = (i < N_NODES * 128) ? s[i] : 0.f;
  h[i] = f2bf(v);
}

// ---------------- Ahat aggregation (bf16 storage, f32 math) ----------------
// out[nl] = alpha * nrm[node] * sum_{s in nbr(node)} hin[s]*nrm[s];  node = base+nl
template<int VEC>
__global__ void k_ahat_bf(const u16* __restrict__ gh, const float* __restrict__ nrm,
                          const int* __restrict__ rowptr, const int* __restrict__ colidx,
                          u16* __restrict__ oh, int F, int base, int nrows, float alpha) {
  int nl = (blockIdx.x * blockDim.x + threadIdx.x) >> 6;
  int lane = threadIdx.x & 63;
  if (nl >= nrows) return;
  int node = base + nl;
  int fo = lane * VEC;
  float res[VEC];
  if (node < N_NODES) {
    float acc[VEC];
#pragma unroll
    for (int v = 0; v < VEC; ++v) acc[v] = 0.f;
    int e0 = rowptr[node], e1 = rowptr[node + 1];
    for (int e = e0; e < e1; ++e) {
      int s = colidx[e];
      float ns = nrm[s];
      const u16* ph = gh + (size_t)s * F + fo;
      if constexpr (VEC == 2) {
        unsigned int uh = *(const unsigned int*)ph;
        acc[0] += bf2f((u16)uh) * ns;
        acc[1] += bf2f((u16)(uh >> 16)) * ns;
      } else {
        uint2 uh = *(const uint2*)ph;
        acc[0] += bf2f((u16)uh.x) * ns;
        acc[1] += bf2f((u16)(uh.x >> 16)) * ns;
        acc[2] += bf2f((u16)uh.y) * ns;
        acc[3] += bf2f((u16)(uh.y >> 16)) * ns;
      }
    }
    float sc = alpha * nrm[node];
#pragma unroll
    for (int v = 0; v < VEC; ++v) res[v] = sc * acc[v];
  } else {
#pragma unroll
    for (int v = 0; v < VEC; ++v) res[v] = 0.f;
  }
  u16* po = oh + (size_t)nl * F + fo;
  if constexpr (VEC == 2) {
    *(unsigned int*)po = (unsigned int)f2bf(res[0]) | ((unsigned int)f2bf(res[1]) << 16);
  } else {
    uint2 w;
    w.x = (unsigned int)f2bf(res[0]) | ((unsigned int)f2bf(res[1]) << 16);
    w.y = (unsigned int)f2bf(res[2]) | ((unsigned int)f2bf(res[3]) << 16);
    *(uint2*)po = w;
  }
}

// ---------------- MFMA GEMM: relu([X0|X1|Y] @ W' + b) ----------------
// 512 threads, 8 waves (2m x 4n), tile 128x128, wave-tile 64x32, BK=32.
// Double-buffered LDS + prefetch: stage(t+1) issued before compute(t); one
// __syncthreads() per K-step (its implicit vmcnt(0) lands after the MFMAs).
template<bool POOL>
__launch_bounds__(512, 4)
__global__ void k_gemm_mfma(const u16* __restrict__ A0, const u16* __restrict__ A1,
                            const u16* __restrict__ A2, int F,
                            const u16* __restrict__ Bth, const u16* __restrict__ Btl,
                            const float* __restrict__ bias, u16* __restrict__ O,
                            float* __restrict__ hg, const int* __restrict__ gid,
                            int fout, int nrows) {
  __shared__ u16 As [2][4][128][8];
  __shared__ u16 Bsh[2][4][128][8];
  __shared__ u16 Bsl[2][4][128][8];
  const int tid = threadIdx.x;
  const int lane = tid & 63, wid = tid >> 6;
  const int wm = wid >> 2, wn = wid & 3;          // 2x4 waves, 64x32 each
  const int row0 = blockIdx.x * 128, col0 = blockIdx.y * 128;
  const int K3 = 3 * F;
  const int li = lane & 15, kq = lane >> 4;
  const int skg = tid >> 7, sidx = tid & 127;     // staging coords (1 glds per tile)
  const size_t dso = (size_t)wid * 512;           // wave-uniform LDS base (u16 units)

  auto stage = [&](int k0, int b) {
    const u16* S; int kk;
    if (k0 < F)          { S = A0; kk = k0; }
    else if (k0 < 2 * F) { S = A1; kk = k0 - F; }
    else                 { S = A2; kk = k0 - 2 * F; }
    size_t ga = (size_t)(row0 + sidx) * F + (kk + skg * 8);
    size_t gb = (size_t)(col0 + sidx) * K3 + (k0 + skg * 8);
    glds16(S + ga,   &As [b][0][0][0] + dso);
    glds16(Bth + gb, &Bsh[b][0][0][0] + dso);
    glds16(Btl + gb, &Bsl[b][0][0][0] + dso);
  };

  f32x4 acc[4][2];
#pragma unroll
  for (int m = 0; m < 4; ++m)
#pragma unroll
    for (int n = 0; n < 2; ++n) acc[m][n] = (f32x4){0.f, 0.f, 0.f, 0.f};

  const int NT = K3 / 32;
  stage(0, 0);
  __syncthreads();
  int cur = 0;
  for (int t = 0; t < NT; ++t) {
    if (t + 1 < NT) stage((t + 1) * 32, cur ^ 1);   // prefetch overlaps compute
    s16x8 a[4], bh[2], bl[2];
#pragma unroll
    for (int m = 0; m < 4; ++m)
      a[m] = *(const s16x8*)&As[cur][kq][wm * 64 + m * 16 + li][0];
#pragma unroll
    for (int n = 0; n < 2; ++n) {
      int cc = wn * 32 + n * 16 + li;
      bh[n] = *(const s16x8*)&Bsh[cur][kq][cc][0];
      bl[n] = *(const s16x8*)&Bsl[cur][kq][cc][0];
    }
#pragma unroll
    for (int m = 0; m < 4; ++m)
#pragma unroll
      for (int n = 0; n < 2; ++n) {
        acc[m][n] = __builtin_amdgcn_mfma_f32_16x16x32_bf16(a[m], bh[n], acc[m][n], 0, 0, 0);
        acc[m][n] = __builtin_amdgcn_mfma_f32_16x16x32_bf16(a[m], bl[n], acc[m][n], 0, 0, 0);
      }
    __syncthreads();   // single barrier: drains prefetch + protects buffer swap
    cur ^= 1;
  }

  if (!POOL) {
#pragma unroll
    for (int m = 0; m < 4; ++m) {
      int rbase = row0 + wm * 64 + m * 16 + kq * 4;
#pragma unroll
      for (int n = 0; n < 2; ++n) {
        int col = col0 + wn * 32 + n * 16 + li;
        float bi = bias[col];
#pragma unroll
        for (int r = 0; r < 4; ++r) {
          int rr = rbase + r;
          if (rr < nrows)
            O[(size_t)rr * fout + col] = f2bf(fmaxf(acc[m][n][r] + bi, 0.f));
        }
      }
    }
  } else {
#pragma unroll
    for (int m = 0; m < 4; ++m) {
      int rbase = row0 + wm * 64 + m * 16 + kq * 4;
      int g4[4];
#pragma unroll
      for (int r = 0; r < 4; ++r) {
        int rr = rbase + r;
        g4[r] = (rr < nrows) ? gid[rr] : -1;
      }
#pragma unroll
      for (int n = 0; n < 2; ++n) {
        int col = col0 + wn * 32 + n * 16 + li;
        float bi = bias[col];
        float sum = 0.f; int curg = g4[0];
#pragma unroll
        for (int r = 0; r < 4; ++r) {
          if (g4[r] != curg) {
            if (curg >= 0) atomicAdd(&hg[curg * 512 + col], sum);
            sum = 0.f; curg = g4[r];
          }
          if (g4[r] >= 0) sum += fmaxf(acc[m][n][r] + bi, 0.f);
        }
        if (curg >= 0) atomicAdd(&hg[curg * 512 + col], sum);
      }
    }
  }
}

// ---------------- MLP head ----------------
__global__ void k_mlp(const float* __restrict__ hg, const float* __restrict__ Wm1,
                      const float* __restrict__ bm1, const float* __restrict__ Wm2,
                      const float* __restrict__ bm2, float* __restrict__ outp) {
  __shared__ float lh[512];
  __shared__ float lt[512];
  int g = blockIdx.x, t = threadIdx.x;
  lh[t] = hg[g * 512 + t];
  __syncthreads();
  float s = bm1[t];
  for (int k = 0; k < 512; ++k) s += lh[k] * Wm1[k * 512 + t];
  lt[t] = fmaxf(s, 0.f);
  __syncthreads();
  if (t < 10) {
    float s2 = bm2[t];
    for (int j = 0; j < 512; ++j) s2 += lt[j] * Wm2[j * 10 + t];
    outp[g * 10 + t] = s2;
  }
}

// ---------------- launch ----------------
extern "C" void kernel_launch(void* const* d_in, const int* in_sizes, int n_in,
                              void* d_out, int out_size, void* d_ws, size_t ws_size,
                              hipStream_t stream) {
  (void)in_sizes; (void)n_in; (void)out_size; (void)ws_size;
  const float* signal = (const float*)d_in[0];
  const float* W0 = (const float*)d_in[1];  const float* b0 = (const float*)d_in[2];
  const float* W1 = (const float*)d_in[3];  const float* b1 = (const float*)d_in[4];
  const float* W2 = (const float*)d_in[5];  const float* b2 = (const float*)d_in[6];
  const float* W3 = (const float*)d_in[7];  const float* b3 = (const float*)d_in[8];
  const float* Wm1 = (const float*)d_in[9];  const float* bm1 = (const float*)d_in[10];
  const float* Wm2 = (const float*)d_in[11]; const float* bm2 = (const float*)d_in[12];
  const int* src = (const int*)d_in[13];
  const int* dst = (const int*)d_in[14];
  const int* gid = (const int*)d_in[15];
  float* outp = (float*)d_out;

  char* ws = (char*)d_ws;
  size_t off = 0;
  auto alloc = [&](size_t b) -> void* {
    void* p = ws + off;
    off = (off + b + 255) & ~(size_t)255;
    return p;
  };
  // total ws footprint ~139 MB (< 145 MB proven safe in round 4)
  int* degi    = (int*)alloc((size_t)N_NODES * 4);
  float* nrm   = (float*)alloc((size_t)N_NODES * 4);
  int* rowptr  = (int*)alloc((size_t)(N_NODES + 1) * 4);
  int* cursor  = (int*)alloc((size_t)N_NODES * 4);
  int* bsum    = (int*)alloc((size_t)SCAN_G * 4);
  int* boff    = (int*)alloc((size_t)SCAN_G * 4);
  int* colidx  = (int*)alloc((size_t)N_EDGES * 4);
  float* hg    = (float*)alloc((size_t)N_GRAPH * 512 * 4);
  u16* Wth0 = (u16*)alloc((size_t)384 * 128 * 2);
  u16* Wtl0 = (u16*)alloc((size_t)384 * 128 * 2);
  u16* Wth1 = (u16*)alloc((size_t)384 * 128 * 2);
  u16* Wtl1 = (u16*)alloc((size_t)384 * 128 * 2);
  u16* Wth2 = (u16*)alloc((size_t)384 * 256 * 2);
  u16* Wtl2 = (u16*)alloc((size_t)384 * 256 * 2);
  u16* Wth3 = (u16*)alloc((size_t)768 * 512 * 2);
  u16* Wtl3 = (u16*)alloc((size_t)768 * 512 * 2);
  u16* QA = (u16*)alloc((size_t)PAD_N * 256 * 2);   // L1 out / L2 in / L3 out / L4 in
  u16* QB = (u16*)alloc((size_t)PAD_N * 128 * 2);   // sig / L2 out / L3 in / L4 Y-chunk
  u16* QX = (u16*)alloc((size_t)PAD_N * 256 * 2);   // X1 (+Y in 2nd half for F=128)

  hipMemsetAsync(degi, 0, (size_t)N_NODES * 4, stream);
  hipMemsetAsync(cursor, 0, (size_t)N_NODES * 4, stream);
  hipMemsetAsync(hg, 0, (size_t)N_GRAPH * 512 * 4, stream);

  k_deg<<<(N_EDGES + 255) / 256, 256, 0, stream>>>(dst, degi);
  k_norm<<<(N_NODES + 255) / 256, 256, 0, stream>>>(degi, nrm);
  k_scan1<<<SCAN_G, SCAN_B, 0, stream>>>(degi, rowptr, bsum);
  k_scan2<<<1, 128, 0, stream>>>(bsum, boff, rowptr);
  k_scan3<<<SCAN_G, SCAN_B, 0, stream>>>(rowptr, boff);
  k_scatter<<<(N_EDGES + 255) / 256, 256, 0, stream>>>(src, dst, rowptr, cursor, colidx);

  k_wsplit<<<(384 * 128 + 255) / 256, 256, 0, stream>>>(W0, Wth0, Wtl0, 128, 128);
  k_wsplit<<<(384 * 128 + 255) / 256, 256, 0, stream>>>(W1, Wth1, Wtl1, 128, 128);
  k_wsplit<<<(384 * 256 + 255) / 256, 256, 0, stream>>>(W2, Wth2, Wtl2, 128, 256);
  k_wsplit<<<(768 * 512 + 255) / 256, 256, 0, stream>>>(W3, Wth3, Wtl3, 256, 512);
  k_sigcast<<<(PAD_N * 128 + 255) / 256, 256, 0, stream>>>(signal, QB);

  const int gfull = (PAD_N + 3) / 4;   // ahat grid, 4 nodes per 256-thread block

  // ---- layers 1-3 (F=128): X1 = QX half0, Y = QX half1, unchunked ----
  u16* X1h = QX;
  u16* Yh  = QX + (size_t)PAD_N * 128;
  auto layer128 = [&](const u16* in, const u16* wth, const u16* wtl,
                      const float* bias, u16* outb, int fout) {
    k_ahat_bf<2><<<gfull, 256, 0, stream>>>(in,  nrm, rowptr, colidx, X1h, 128, 0, PAD_N, -1.f);
    k_ahat_bf<2><<<gfull, 256, 0, stream>>>(X1h, nrm, rowptr, colidx, Yh,  128, 0, PAD_N,  1.f);
    dim3 gg(PAD_N / 128, fout / 128);
    k_gemm_mfma<false><<<gg, 512, 0, stream>>>(in, X1h, Yh, 128, wth, wtl, bias,
                                               outb, nullptr, nullptr, fout, N_NODES);
  };
  layer128(QB, Wth0, Wtl0, b0, QA, 128);
  layer128(QA, Wth1, Wtl1, b1, QB, 128);
  layer128(QB, Wth2, Wtl2, b2, QA, 256);

  // ---- layer 4 (F=256, fout=512, pooled): X1 = QX full; Y chunks in QB ----
  k_ahat_bf<4><<<gfull, 256, 0, stream>>>(QA, nrm, rowptr, colidx, QX, 256, 0, PAD_N, -1.f);
  const int CH4 = 50048;   // CH4*256*2 bytes == QB capacity; multiple of 128
  for (int base = 0; base < N_NODES; base += CH4) {
    int nr = (N_NODES - base < CH4) ? (N_NODES - base) : CH4;
    k_ahat_bf<4><<<(nr + 3) / 4, 256, 0, stream>>>(QX, nrm, rowptr, colidx, QB,
                                                   256, base, nr, 1.f);
    dim3 gg((nr + 127) / 128, 4);
    k_gemm_mfma<true><<<gg, 512, 0, stream>>>(
        QA + (size_t)base * 256, QX + (size_t)base * 256, QB, 256,
        Wth3, Wtl3, b3, nullptr, hg, gid + base, 512, nr);
  }

  k_mlp<<<N_GRAPH, 512, 0, stream>>>(hg, Wm1, bm1, Wm2, bm2, outp);
}

// Round 7
// 2234.390 us; speedup vs baseline: 2.8188x; 1.0538x over previous
//
#include <hip/hip_runtime.h>
#include <hip/hip_bf16.h>

#define N_NODES 100000
#define PAD_N   100096   // multiple of 128
#define N_EDGES 1600000
#define N_GRAPH 128
#define SCAN_B  1024
#define SCAN_G  ((N_NODES + SCAN_B - 1) / SCAN_B)   // 98

typedef unsigned short u16;
typedef __attribute__((ext_vector_type(4))) float f32x4;
typedef __attribute__((ext_vector_type(8))) short s16x8;

__device__ __forceinline__ float bf2f(u16 u) {
  unsigned int v = ((unsigned int)u) << 16;
  float f; __builtin_memcpy(&f, &v, 4); return f;
}
__device__ __forceinline__ u16 f2bf(float f) {
  unsigned int v; __builtin_memcpy(&v, &f, 4);
  return (u16)((v + 0x7FFFu + ((v >> 16) & 1u)) >> 16);
}
__device__ __forceinline__ void split2(float v, u16& h, u16& l) {
  h = f2bf(v);
  l = f2bf(v - bf2f(h));
}
__device__ __forceinline__ void glds16(const u16* g, u16* l) {
  __builtin_amdgcn_global_load_lds(
      (const __attribute__((address_space(1))) unsigned int*)g,
      (__attribute__((address_space(3))) unsigned int*)l, 16, 0, 0);
}

// ---------------- graph preprocessing ----------------
__global__ void k_deg(const int* __restrict__ dst, int* __restrict__ degi) {
  int e = blockIdx.x * 256 + threadIdx.x;
  if (e < N_EDGES) atomicAdd(&degi[dst[e]], 1);
}

__global__ void k_norm(const int* __restrict__ degi, float* __restrict__ nrm) {
  int i = blockIdx.x * 256 + threadIdx.x;
  if (i < N_NODES) {
    int d = degi[i]; if (d < 1) d = 1;
    nrm[i] = 1.0f / sqrtf((float)d);
  }
}

// hierarchical exclusive scan: per-block scan -> scan block sums -> add offsets
__global__ void k_scan1(const int* __restrict__ degi, int* __restrict__ rowptr,
                        int* __restrict__ bsum) {
  __shared__ int sm[SCAN_B];
  int i = blockIdx.x * SCAN_B + threadIdx.x;
  int v = (i < N_NODES) ? degi[i] : 0;
  sm[threadIdx.x] = v;
  __syncthreads();
  for (int off = 1; off < SCAN_B; off <<= 1) {
    int t = (threadIdx.x >= off) ? sm[threadIdx.x - off] : 0;
    __syncthreads();
    sm[threadIdx.x] += t;
    __syncthreads();
  }
  if (i < N_NODES) rowptr[i] = sm[threadIdx.x] - v;   // block-local exclusive
  if (threadIdx.x == SCAN_B - 1) bsum[blockIdx.x] = sm[SCAN_B - 1];
}

__global__ void k_scan2(const int* __restrict__ bsum, int* __restrict__ boff,
                        int* __restrict__ rowptr) {
  __shared__ int sm[128];
  int v = (threadIdx.x < SCAN_G) ? bsum[threadIdx.x] : 0;
  sm[threadIdx.x] = v;
  __syncthreads();
  for (int off = 1; off < 128; off <<= 1) {
    int t = (threadIdx.x >= off) ? sm[threadIdx.x - off] : 0;
    __syncthreads();
    sm[threadIdx.x] += t;
    __syncthreads();
  }
  if (threadIdx.x < SCAN_G) boff[threadIdx.x] = sm[threadIdx.x] - v;
  if (threadIdx.x == 127) rowptr[N_NODES] = sm[127];
}

__global__ void k_scan3(int* __restrict__ rowptr, const int* __restrict__ boff) {
  int i = blockIdx.x * SCAN_B + threadIdx.x;
  if (i < N_NODES) rowptr[i] += boff[blockIdx.x];
}

__global__ void k_scatter(const int* __restrict__ src, const int* __restrict__ dst,
                          const int* __restrict__ rowptr, int* __restrict__ cursor,
                          int* __restrict__ colidx) {
  int e = blockIdx.x * 256 + threadIdx.x;
  if (e >= N_EDGES) return;
  int d = dst[e];
  int p = atomicAdd(&cursor[d], 1);
  colidx[rowptr[d] + p] = src[e];
}

// ---------------- weight transform + split ----------------
// Logical weights for GEMM over [X0 | X1 | Y=Ahat X1]:
//   rows [0,F): Wa - Wc ; rows [F,2F): Wb ; rows [2F,3F): -2*Wc
// stored transposed [fout][K3] as hi/lo bf16 planes.
__global__ void k_wsplit(const float* __restrict__ W, u16* __restrict__ th,
                         u16* __restrict__ tl, int F, int fout) {
  int K3 = 3 * F;
  int i = blockIdx.x * 256 + threadIdx.x;
  if (i >= K3 * fout) return;
  int k = i / fout, n = i % fout;
  float v;
  if (k < F)          v = W[(size_t)k * fout + n] - W[(size_t)(k + 2 * F) * fout + n];
  else if (k < 2 * F) v = W[(size_t)k * fout + n];
  else                v = -2.0f * W[(size_t)k * fout + n];
  u16 h, l; split2(v, h, l);
  th[(size_t)n * K3 + k] = h;
  tl[(size_t)n * K3 + k] = l;
}

__global__ void k_sigcast(const float* __restrict__ s, u16* __restrict__ h) {
  int i = blockIdx.x * 256 + threadIdx.x;
  if (i >= PAD_N * 128) return;
  float v = (i < N_NODES * 128) ? s[i] : 0.f;
  h[i] = f2bf(v);
}

// ---------------- Ahat aggregation (bf16 storage, f32 math) ----------------
// out[nl] = alpha * nrm[node] * sum_{s in nbr(node)} hin[s]*nrm[s];  node = base+nl
template<int VEC>
__global__ void k_ahat_bf(const u16* __restrict__ gh, const float* __restrict__ nrm,
                          const int* __restrict__ rowptr, const int* __restrict__ colidx,
                          u16* __restrict__ oh, int F, int base, int nrows, float alpha) {
  int nl = (blockIdx.x * blockDim.x + threadIdx.x) >> 6;
  int lane = threadIdx.x & 63;
  if (nl >= nrows) return;
  int node = base + nl;
  int fo = lane * VEC;
  float res[VEC];
  if (node < N_NODES) {
    float acc[VEC];
#pragma unroll
    for (int v = 0; v < VEC; ++v) acc[v] = 0.f;
    int e0 = rowptr[node], e1 = rowptr[node + 1];
    for (int e = e0; e < e1; ++e) {
      int s = colidx[e];
      float ns = nrm[s];
      const u16* ph = gh + (size_t)s * F + fo;
      if constexpr (VEC == 2) {
        unsigned int uh = *(const unsigned int*)ph;
        acc[0] += bf2f((u16)uh) * ns;
        acc[1] += bf2f((u16)(uh >> 16)) * ns;
      } else {
        uint2 uh = *(const uint2*)ph;
        acc[0] += bf2f((u16)uh.x) * ns;
        acc[1] += bf2f((u16)(uh.x >> 16)) * ns;
        acc[2] += bf2f((u16)uh.y) * ns;
        acc[3] += bf2f((u16)(uh.y >> 16)) * ns;
      }
    }
    float sc = alpha * nrm[node];
#pragma unroll
    for (int v = 0; v < VEC; ++v) res[v] = sc * acc[v];
  } else {
#pragma unroll
    for (int v = 0; v < VEC; ++v) res[v] = 0.f;
  }
  u16* po = oh + (size_t)nl * F + fo;
  if constexpr (VEC == 2) {
    *(unsigned int*)po = (unsigned int)f2bf(res[0]) | ((unsigned int)f2bf(res[1]) << 16);
  } else {
    uint2 w;
    w.x = (unsigned int)f2bf(res[0]) | ((unsigned int)f2bf(res[1]) << 16);
    w.y = (unsigned int)f2bf(res[2]) | ((unsigned int)f2bf(res[3]) << 16);
    *(uint2*)po = w;
  }
}

// ---------------- MFMA GEMM: relu([X0|X1|Y] @ W' + b) ----------------
// 512 threads, 8 waves (2m x 4n), tile 128x128, wave-tile 64x32, BK=32.
// 3-deep counted-vmcnt pipeline (T3+T4): stages t..t+2 in flight; per iter:
//   waitcnt vmcnt(6) -> barrier -> ds_read -> lgkmcnt(0)+sched_barrier ->
//   barrier -> stage(t+3) into just-consumed buffer -> MFMA cluster.
// Grid: x = col-block, y = row-block (col-blocks of one row-panel run
// concurrently -> A fetched once from HBM, re-hit in L2/L3).
template<bool POOL>
__launch_bounds__(512, 4)
__global__ void k_gemm_mfma(const u16* __restrict__ A0, const u16* __restrict__ A1,
                            const u16* __restrict__ A2, int F,
                            const u16* __restrict__ Bth, const u16* __restrict__ Btl,
                            const float* __restrict__ bias, u16* __restrict__ O,
                            float* __restrict__ hg, const int* __restrict__ gid,
                            int fout, int nrows) {
  __shared__ u16 As [3][4][128][8];
  __shared__ u16 Bsh[3][4][128][8];
  __shared__ u16 Bsl[3][4][128][8];
  const int tid = threadIdx.x;
  const int lane = tid & 63, wid = tid >> 6;
  const int wm = wid >> 2, wn = wid & 3;          // 2x4 waves, 64x32 each
  const int row0 = blockIdx.y * 128, col0 = blockIdx.x * 128;
  const int K3 = 3 * F;
  const int li = lane & 15, kq = lane >> 4;
  const int skg = tid >> 7, sidx = tid & 127;     // staging coords
  const size_t dso = (size_t)wid * 512;           // wave-uniform LDS base (u16 units)

  auto stage = [&](int t, int b) {
    int k0 = t * 32;
    const u16* S; int kk;
    if (k0 < F)          { S = A0; kk = k0; }
    else if (k0 < 2 * F) { S = A1; kk = k0 - F; }
    else                 { S = A2; kk = k0 - 2 * F; }
    size_t ga = (size_t)(row0 + sidx) * F + (kk + skg * 8);
    size_t gb = (size_t)(col0 + sidx) * K3 + (k0 + skg * 8);
    glds16(S + ga,   &As [b][0][0][0] + dso);
    glds16(Bth + gb, &Bsh[b][0][0][0] + dso);
    glds16(Btl + gb, &Bsl[b][0][0][0] + dso);
  };

  f32x4 acc[4][2];
#pragma unroll
  for (int m = 0; m < 4; ++m)
#pragma unroll
    for (int n = 0; n < 2; ++n) acc[m][n] = (f32x4){0.f, 0.f, 0.f, 0.f};

  const int NT = K3 / 32;                         // 12 or 24
  stage(0, 0);
  stage(1, 1);
  stage(2, 2);
  for (int t = 0; t < NT; ++t) {
    // wait until MY stage-t loads landed, leaving later stages in flight
    int rem = (NT - 1 - t);                       // stages ahead of t still in flight
    if (rem >= 2)      asm volatile("s_waitcnt vmcnt(6)" ::: "memory");
    else if (rem == 1) asm volatile("s_waitcnt vmcnt(3)" ::: "memory");
    else               asm volatile("s_waitcnt vmcnt(0)" ::: "memory");
    __builtin_amdgcn_s_barrier();                 // all waves' stage-t writes visible
    const int cb = t % 3;
    s16x8 a[4], bh[2], bl[2];
#pragma unroll
    for (int m = 0; m < 4; ++m)
      a[m] = *(const s16x8*)&As[cb][kq][wm * 64 + m * 16 + li][0];
#pragma unroll
    for (int n = 0; n < 2; ++n) {
      int cc = wn * 32 + n * 16 + li;
      bh[n] = *(const s16x8*)&Bsh[cb][kq][cc][0];
      bl[n] = *(const s16x8*)&Bsl[cb][kq][cc][0];
    }
    asm volatile("s_waitcnt lgkmcnt(0)" ::: "memory");  // frags in registers
    __builtin_amdgcn_sched_barrier(0);            // rule 18: pin order
    __builtin_amdgcn_s_barrier();                 // all waves done reading buf cb
    if (t + 3 < NT) stage(t + 3, cb);             // refill consumed buffer early
#pragma unroll
    for (int m = 0; m < 4; ++m)
#pragma unroll
      for (int n = 0; n < 2; ++n) {
        acc[m][n] = __builtin_amdgcn_mfma_f32_16x16x32_bf16(a[m], bh[n], acc[m][n], 0, 0, 0);
        acc[m][n] = __builtin_amdgcn_mfma_f32_16x16x32_bf16(a[m], bl[n], acc[m][n], 0, 0, 0);
      }
  }

  if (!POOL) {
#pragma unroll
    for (int m = 0; m < 4; ++m) {
      int rbase = row0 + wm * 64 + m * 16 + kq * 4;
#pragma unroll
      for (int n = 0; n < 2; ++n) {
        int col = col0 + wn * 32 + n * 16 + li;
        float bi = bias[col];
#pragma unroll
        for (int r = 0; r < 4; ++r) {
          int rr = rbase + r;
          if (rr < nrows)
            O[(size_t)rr * fout + col] = f2bf(fmaxf(acc[m][n][r] + bi, 0.f));
        }
      }
    }
  } else {
#pragma unroll
    for (int m = 0; m < 4; ++m) {
      int rbase = row0 + wm * 64 + m * 16 + kq * 4;
      int g4[4];
#pragma unroll
      for (int r = 0; r < 4; ++r) {
        int rr = rbase + r;
        g4[r] = (rr < nrows) ? gid[rr] : -1;
      }
#pragma unroll
      for (int n = 0; n < 2; ++n) {
        int col = col0 + wn * 32 + n * 16 + li;
        float bi = bias[col];
        float sum = 0.f; int curg = g4[0];
#pragma unroll
        for (int r = 0; r < 4; ++r) {
          if (g4[r] != curg) {
            if (curg >= 0) atomicAdd(&hg[curg * 512 + col], sum);
            sum = 0.f; curg = g4[r];
          }
          if (g4[r] >= 0) sum += fmaxf(acc[m][n][r] + bi, 0.f);
        }
        if (curg >= 0) atomicAdd(&hg[curg * 512 + col], sum);
      }
    }
  }
}

// ---------------- MLP head ----------------
__global__ void k_mlp(const float* __restrict__ hg, const float* __restrict__ Wm1,
                      const float* __restrict__ bm1, const float* __restrict__ Wm2,
                      const float* __restrict__ bm2, float* __restrict__ outp) {
  __shared__ float lh[512];
  __shared__ float lt[512];
  int g = blockIdx.x, t = threadIdx.x;
  lh[t] = hg[g * 512 + t];
  __syncthreads();
  float s = bm1[t];
  for (int k = 0; k < 512; ++k) s += lh[k] * Wm1[k * 512 + t];
  lt[t] = fmaxf(s, 0.f);
  __syncthreads();
  if (t < 10) {
    float s2 = bm2[t];
    for (int j = 0; j < 512; ++j) s2 += lt[j] * Wm2[j * 10 + t];
    outp[g * 10 + t] = s2;
  }
}

// ---------------- launch ----------------
extern "C" void kernel_launch(void* const* d_in, const int* in_sizes, int n_in,
                              void* d_out, int out_size, void* d_ws, size_t ws_size,
                              hipStream_t stream) {
  (void)in_sizes; (void)n_in; (void)out_size; (void)ws_size;
  const float* signal = (const float*)d_in[0];
  const float* W0 = (const float*)d_in[1];  const float* b0 = (const float*)d_in[2];
  const float* W1 = (const float*)d_in[3];  const float* b1 = (const float*)d_in[4];
  const float* W2 = (const float*)d_in[5];  const float* b2 = (const float*)d_in[6];
  const float* W3 = (const float*)d_in[7];  const float* b3 = (const float*)d_in[8];
  const float* Wm1 = (const float*)d_in[9];  const float* bm1 = (const float*)d_in[10];
  const float* Wm2 = (const float*)d_in[11]; const float* bm2 = (const float*)d_in[12];
  const int* src = (const int*)d_in[13];
  const int* dst = (const int*)d_in[14];
  const int* gid = (const int*)d_in[15];
  float* outp = (float*)d_out;

  char* ws = (char*)d_ws;
  size_t off = 0;
  auto alloc = [&](size_t b) -> void* {
    void* p = ws + off;
    off = (off + b + 255) & ~(size_t)255;
    return p;
  };
  // total ws footprint ~139 MB (< 145 MB proven safe in round 4)
  int* degi    = (int*)alloc((size_t)N_NODES * 4);
  float* nrm   = (float*)alloc((size_t)N_NODES * 4);
  int* rowptr  = (int*)alloc((size_t)(N_NODES + 1) * 4);
  int* cursor  = (int*)alloc((size_t)N_NODES * 4);
  int* bsum    = (int*)alloc((size_t)SCAN_G * 4);
  int* boff    = (int*)alloc((size_t)SCAN_G * 4);
  int* colidx  = (int*)alloc((size_t)N_EDGES * 4);
  float* hg    = (float*)alloc((size_t)N_GRAPH * 512 * 4);
  u16* Wth0 = (u16*)alloc((size_t)384 * 128 * 2);
  u16* Wtl0 = (u16*)alloc((size_t)384 * 128 * 2);
  u16* Wth1 = (u16*)alloc((size_t)384 * 128 * 2);
  u16* Wtl1 = (u16*)alloc((size_t)384 * 128 * 2);
  u16* Wth2 = (u16*)alloc((size_t)384 * 256 * 2);
  u16* Wtl2 = (u16*)alloc((size_t)384 * 256 * 2);
  u16* Wth3 = (u16*)alloc((size_t)768 * 512 * 2);
  u16* Wtl3 = (u16*)alloc((size_t)768 * 512 * 2);
  u16* QA = (u16*)alloc((size_t)PAD_N * 256 * 2);   // L1 out / L2 in / L3 out / L4 in
  u16* QB = (u16*)alloc((size_t)PAD_N * 128 * 2);   // sig / L2 out / L3 in / L4 Y-chunk
  u16* QX = (u16*)alloc((size_t)PAD_N * 256 * 2);   // X1 (+Y in 2nd half for F=128)

  hipMemsetAsync(degi, 0, (size_t)N_NODES * 4, stream);
  hipMemsetAsync(cursor, 0, (size_t)N_NODES * 4, stream);
  hipMemsetAsync(hg, 0, (size_t)N_GRAPH * 512 * 4, stream);

  k_deg<<<(N_EDGES + 255) / 256, 256, 0, stream>>>(dst, degi);
  k_norm<<<(N_NODES + 255) / 256, 256, 0, stream>>>(degi, nrm);
  k_scan1<<<SCAN_G, SCAN_B, 0, stream>>>(degi, rowptr, bsum);
  k_scan2<<<1, 128, 0, stream>>>(bsum, boff, rowptr);
  k_scan3<<<SCAN_G, SCAN_B, 0, stream>>>(rowptr, boff);
  k_scatter<<<(N_EDGES + 255) / 256, 256, 0, stream>>>(src, dst, rowptr, cursor, colidx);

  k_wsplit<<<(384 * 128 + 255) / 256, 256, 0, stream>>>(W0, Wth0, Wtl0, 128, 128);
  k_wsplit<<<(384 * 128 + 255) / 256, 256, 0, stream>>>(W1, Wth1, Wtl1, 128, 128);
  k_wsplit<<<(384 * 256 + 255) / 256, 256, 0, stream>>>(W2, Wth2, Wtl2, 128, 256);
  k_wsplit<<<(768 * 512 + 255) / 256, 256, 0, stream>>>(W3, Wth3, Wtl3, 256, 512);
  k_sigcast<<<(PAD_N * 128 + 255) / 256, 256, 0, stream>>>(signal, QB);

  const int gfull = (PAD_N + 3) / 4;   // ahat grid, 4 nodes per 256-thread block

  // ---- layers 1-3 (F=128): X1 = QX half0, Y = QX half1, unchunked ----
  u16* X1h = QX;
  u16* Yh  = QX + (size_t)PAD_N * 128;
  auto layer128 = [&](const u16* in, const u16* wth, const u16* wtl,
                      const float* bias, u16* outb, int fout) {
    k_ahat_bf<2><<<gfull, 256, 0, stream>>>(in,  nrm, rowptr, colidx, X1h, 128, 0, PAD_N, -1.f);
    k_ahat_bf<2><<<gfull, 256, 0, stream>>>(X1h, nrm, rowptr, colidx, Yh,  128, 0, PAD_N,  1.f);
    dim3 gg(fout / 128, PAD_N / 128);   // x = col-block, y = row-block
    k_gemm_mfma<false><<<gg, 512, 0, stream>>>(in, X1h, Yh, 128, wth, wtl, bias,
                                               outb, nullptr, nullptr, fout, N_NODES);
  };
  layer128(QB, Wth0, Wtl0, b0, QA, 128);
  layer128(QA, Wth1, Wtl1, b1, QB, 128);
  layer128(QB, Wth2, Wtl2, b2, QA, 256);

  // ---- layer 4 (F=256, fout=512, pooled): X1 = QX full; Y chunks in QB ----
  k_ahat_bf<4><<<gfull, 256, 0, stream>>>(QA, nrm, rowptr, colidx, QX, 256, 0, PAD_N, -1.f);
  const int CH4 = 50048;   // CH4*256*2 bytes == QB capacity; multiple of 128
  for (int base = 0; base < N_NODES; base += CH4) {
    int nr = (N_NODES - base < CH4) ? (N_NODES - base) : CH4;
    k_ahat_bf<4><<<(nr + 3) / 4, 256, 0, stream>>>(QX, nrm, rowptr, colidx, QB,
                                                   256, base, nr, 1.f);
    dim3 gg(4, (nr + 127) / 128);       // x = col-block, y = row-block
    k_gemm_mfma<true><<<gg, 512, 0, stream>>>(
        QA + (size_t)base * 256, QX + (size_t)base * 256, QB, 256,
        Wth3, Wtl3, b3, nullptr, hg, gid + base, 512, nr);
  }

  k_mlp<<<N_GRAPH, 512, 0, stream>>>(hg, Wm1, bm1, Wm2, bm2, outp);
}

// Round 8
// 1634.778 us; speedup vs baseline: 3.8528x; 1.3668x over previous
//
#include <hip/hip_runtime.h>
#include <hip/hip_bf16.h>

#define N_NODES 100000
#define PAD_N   100096   // multiple of 128
#define N_EDGES 1600000
#define N_GRAPH 128
#define SCAN_B  1024
#define SCAN_G  ((N_NODES + SCAN_B - 1) / SCAN_B)   // 98

typedef unsigned short u16;
typedef __attribute__((ext_vector_type(4))) float f32x4;
typedef __attribute__((ext_vector_type(8))) short s16x8;

__device__ __forceinline__ float bf2f(u16 u) {
  unsigned int v = ((unsigned int)u) << 16;
  float f; __builtin_memcpy(&f, &v, 4); return f;
}
__device__ __forceinline__ u16 f2bf(float f) {
  unsigned int v; __builtin_memcpy(&v, &f, 4);
  return (u16)((v + 0x7FFFu + ((v >> 16) & 1u)) >> 16);
}
__device__ __forceinline__ void split2(float v, u16& h, u16& l) {
  h = f2bf(v);
  l = f2bf(v - bf2f(h));
}
__device__ __forceinline__ void glds16(const u16* g, u16* l) {
  __builtin_amdgcn_global_load_lds(
      (const __attribute__((address_space(1))) unsigned int*)g,
      (__attribute__((address_space(3))) unsigned int*)l, 16, 0, 0);
}

// ---------------- graph preprocessing ----------------
__global__ void k_deg(const int* __restrict__ dst, int* __restrict__ degi) {
  int e = blockIdx.x * 256 + threadIdx.x;
  if (e < N_EDGES) atomicAdd(&degi[dst[e]], 1);
}

__global__ void k_norm(const int* __restrict__ degi, float* __restrict__ nrm) {
  int i = blockIdx.x * 256 + threadIdx.x;
  if (i < N_NODES) {
    int d = degi[i]; if (d < 1) d = 1;
    nrm[i] = 1.0f / sqrtf((float)d);
  }
}

// hierarchical exclusive scan: per-block scan -> scan block sums -> add offsets
__global__ void k_scan1(const int* __restrict__ degi, int* __restrict__ rowptr,
                        int* __restrict__ bsum) {
  __shared__ int sm[SCAN_B];
  int i = blockIdx.x * SCAN_B + threadIdx.x;
  int v = (i < N_NODES) ? degi[i] : 0;
  sm[threadIdx.x] = v;
  __syncthreads();
  for (int off = 1; off < SCAN_B; off <<= 1) {
    int t = (threadIdx.x >= off) ? sm[threadIdx.x - off] : 0;
    __syncthreads();
    sm[threadIdx.x] += t;
    __syncthreads();
  }
  if (i < N_NODES) rowptr[i] = sm[threadIdx.x] - v;   // block-local exclusive
  if (threadIdx.x == SCAN_B - 1) bsum[blockIdx.x] = sm[SCAN_B - 1];
}

__global__ void k_scan2(const int* __restrict__ bsum, int* __restrict__ boff,
                        int* __restrict__ rowptr) {
  __shared__ int sm[128];
  int v = (threadIdx.x < SCAN_G) ? bsum[threadIdx.x] : 0;
  sm[threadIdx.x] = v;
  __syncthreads();
  for (int off = 1; off < 128; off <<= 1) {
    int t = (threadIdx.x >= off) ? sm[threadIdx.x - off] : 0;
    __syncthreads();
    sm[threadIdx.x] += t;
    __syncthreads();
  }
  if (threadIdx.x < SCAN_G) boff[threadIdx.x] = sm[threadIdx.x] - v;
  if (threadIdx.x == 127) rowptr[N_NODES] = sm[127];
}

__global__ void k_scan3(int* __restrict__ rowptr, const int* __restrict__ boff) {
  int i = blockIdx.x * SCAN_B + threadIdx.x;
  if (i < N_NODES) rowptr[i] += boff[blockIdx.x];
}

__global__ void k_scatter(const int* __restrict__ src, const int* __restrict__ dst,
                          const int* __restrict__ rowptr, int* __restrict__ cursor,
                          int* __restrict__ colidx) {
  int e = blockIdx.x * 256 + threadIdx.x;
  if (e >= N_EDGES) return;
  int d = dst[e];
  int p = atomicAdd(&cursor[d], 1);
  colidx[rowptr[d] + p] = src[e];
}

// ---------------- weight transform + split ----------------
// Logical weights for GEMM over [X0 | X1 | Y=Ahat X1]:
//   rows [0,F): Wa - Wc ; rows [F,2F): Wb ; rows [2F,3F): -2*Wc
// stored transposed [fout][K3] as hi/lo bf16 planes.
__global__ void k_wsplit(const float* __restrict__ W, u16* __restrict__ th,
                         u16* __restrict__ tl, int F, int fout) {
  int K3 = 3 * F;
  int i = blockIdx.x * 256 + threadIdx.x;
  if (i >= K3 * fout) return;
  int k = i / fout, n = i % fout;
  float v;
  if (k < F)          v = W[(size_t)k * fout + n] - W[(size_t)(k + 2 * F) * fout + n];
  else if (k < 2 * F) v = W[(size_t)k * fout + n];
  else                v = -2.0f * W[(size_t)k * fout + n];
  u16 h, l; split2(v, h, l);
  th[(size_t)n * K3 + k] = h;
  tl[(size_t)n * K3 + k] = l;
}

__global__ void k_sigcast(const float* __restrict__ s, u16* __restrict__ h) {
  int i = blockIdx.x * 256 + threadIdx.x;
  if (i >= PAD_N * 128) return;
  float v = (i < N_NODES * 128) ? s[i] : 0.f;
  h[i] = f2bf(v);
}

// ---------------- Ahat aggregation (bf16 storage, f32 math) ----------------
// out[nl] = alpha * nrm[node] * sum_{s in nbr(node)} hin[s]*nrm[s];  node = base+nl
// 4x edge unroll: 4 independent row-gathers in flight per wave (latency hiding).
// Accumulation order (e, e+1, e+2, e+3) identical to the serial loop.
template<int VEC>
__global__ void k_ahat_bf(const u16* __restrict__ gh, const float* __restrict__ nrm,
                          const int* __restrict__ rowptr, const int* __restrict__ colidx,
                          u16* __restrict__ oh, int F, int base, int nrows, float alpha) {
  int nl = (blockIdx.x * blockDim.x + threadIdx.x) >> 6;
  int lane = threadIdx.x & 63;
  if (nl >= nrows) return;
  int node = base + nl;
  int fo = lane * VEC;
  float res[VEC];
  if (node < N_NODES) {
    float acc[VEC];
#pragma unroll
    for (int v = 0; v < VEC; ++v) acc[v] = 0.f;
    int e0 = rowptr[node], e1 = rowptr[node + 1];
    int e = e0;
    for (; e + 4 <= e1; e += 4) {
      int sa = colidx[e], sb = colidx[e + 1], sc = colidx[e + 2], sd = colidx[e + 3];
      float na = nrm[sa], nb = nrm[sb], nc = nrm[sc], nd = nrm[sd];
      if constexpr (VEC == 2) {
        unsigned int ua = *(const unsigned int*)(gh + (size_t)sa * F + fo);
        unsigned int ub = *(const unsigned int*)(gh + (size_t)sb * F + fo);
        unsigned int uc = *(const unsigned int*)(gh + (size_t)sc * F + fo);
        unsigned int ud = *(const unsigned int*)(gh + (size_t)sd * F + fo);
        acc[0] += bf2f((u16)ua) * na; acc[1] += bf2f((u16)(ua >> 16)) * na;
        acc[0] += bf2f((u16)ub) * nb; acc[1] += bf2f((u16)(ub >> 16)) * nb;
        acc[0] += bf2f((u16)uc) * nc; acc[1] += bf2f((u16)(uc >> 16)) * nc;
        acc[0] += bf2f((u16)ud) * nd; acc[1] += bf2f((u16)(ud >> 16)) * nd;
      } else {
        uint2 ua = *(const uint2*)(gh + (size_t)sa * F + fo);
        uint2 ub = *(const uint2*)(gh + (size_t)sb * F + fo);
        uint2 uc = *(const uint2*)(gh + (size_t)sc * F + fo);
        uint2 ud = *(const uint2*)(gh + (size_t)sd * F + fo);
        acc[0] += bf2f((u16)ua.x) * na; acc[1] += bf2f((u16)(ua.x >> 16)) * na;
        acc[2] += bf2f((u16)ua.y) * na; acc[3] += bf2f((u16)(ua.y >> 16)) * na;
        acc[0] += bf2f((u16)ub.x) * nb; acc[1] += bf2f((u16)(ub.x >> 16)) * nb;
        acc[2] += bf2f((u16)ub.y) * nb; acc[3] += bf2f((u16)(ub.y >> 16)) * nb;
        acc[0] += bf2f((u16)uc.x) * nc; acc[1] += bf2f((u16)(uc.x >> 16)) * nc;
        acc[2] += bf2f((u16)uc.y) * nc; acc[3] += bf2f((u16)(uc.y >> 16)) * nc;
        acc[0] += bf2f((u16)ud.x) * nd; acc[1] += bf2f((u16)(ud.x >> 16)) * nd;
        acc[2] += bf2f((u16)ud.y) * nd; acc[3] += bf2f((u16)(ud.y >> 16)) * nd;
      }
    }
    for (; e < e1; ++e) {
      int s = colidx[e];
      float ns = nrm[s];
      const u16* ph = gh + (size_t)s * F + fo;
      if constexpr (VEC == 2) {
        unsigned int uh = *(const unsigned int*)ph;
        acc[0] += bf2f((u16)uh) * ns;
        acc[1] += bf2f((u16)(uh >> 16)) * ns;
      } else {
        uint2 uh = *(const uint2*)ph;
        acc[0] += bf2f((u16)uh.x) * ns;
        acc[1] += bf2f((u16)(uh.x >> 16)) * ns;
        acc[2] += bf2f((u16)uh.y) * ns;
        acc[3] += bf2f((u16)(uh.y >> 16)) * ns;
      }
    }
    float sc2 = alpha * nrm[node];
#pragma unroll
    for (int v = 0; v < VEC; ++v) res[v] = sc2 * acc[v];
  } else {
#pragma unroll
    for (int v = 0; v < VEC; ++v) res[v] = 0.f;
  }
  u16* po = oh + (size_t)nl * F + fo;
  if constexpr (VEC == 2) {
    *(unsigned int*)po = (unsigned int)f2bf(res[0]) | ((unsigned int)f2bf(res[1]) << 16);
  } else {
    uint2 w;
    w.x = (unsigned int)f2bf(res[0]) | ((unsigned int)f2bf(res[1]) << 16);
    w.y = (unsigned int)f2bf(res[2]) | ((unsigned int)f2bf(res[3]) << 16);
    *(uint2*)po = w;
  }
}

// ---------------- MFMA GEMM: relu([X0|X1|Y] @ W' + b) ----------------
// 512 threads, 8 waves (2m x 4n), tile 128x128, wave-tile 64x32, BK=32.
// 3-deep counted-vmcnt pipeline (T3+T4) + setprio around MFMA cluster (T5).
template<bool POOL>
__launch_bounds__(512, 4)
__global__ void k_gemm_mfma(const u16* __restrict__ A0, const u16* __restrict__ A1,
                            const u16* __restrict__ A2, int F,
                            const u16* __restrict__ Bth, const u16* __restrict__ Btl,
                            const float* __restrict__ bias, u16* __restrict__ O,
                            float* __restrict__ hg, const int* __restrict__ gid,
                            int fout, int nrows) {
  __shared__ u16 As [3][4][128][8];
  __shared__ u16 Bsh[3][4][128][8];
  __shared__ u16 Bsl[3][4][128][8];
  const int tid = threadIdx.x;
  const int lane = tid & 63, wid = tid >> 6;
  const int wm = wid >> 2, wn = wid & 3;          // 2x4 waves, 64x32 each
  const int row0 = blockIdx.y * 128, col0 = blockIdx.x * 128;
  const int K3 = 3 * F;
  const int li = lane & 15, kq = lane >> 4;
  const int skg = tid >> 7, sidx = tid & 127;     // staging coords
  const size_t dso = (size_t)wid * 512;           // wave-uniform LDS base (u16 units)

  auto stage = [&](int t, int b) {
    int k0 = t * 32;
    const u16* S; int kk;
    if (k0 < F)          { S = A0; kk = k0; }
    else if (k0 < 2 * F) { S = A1; kk = k0 - F; }
    else                 { S = A2; kk = k0 - 2 * F; }
    size_t ga = (size_t)(row0 + sidx) * F + (kk + skg * 8);
    size_t gb = (size_t)(col0 + sidx) * K3 + (k0 + skg * 8);
    glds16(S + ga,   &As [b][0][0][0] + dso);
    glds16(Bth + gb, &Bsh[b][0][0][0] + dso);
    glds16(Btl + gb, &Bsl[b][0][0][0] + dso);
  };

  f32x4 acc[4][2];
#pragma unroll
  for (int m = 0; m < 4; ++m)
#pragma unroll
    for (int n = 0; n < 2; ++n) acc[m][n] = (f32x4){0.f, 0.f, 0.f, 0.f};

  const int NT = K3 / 32;                         // 12 or 24
  stage(0, 0);
  stage(1, 1);
  stage(2, 2);
  for (int t = 0; t < NT; ++t) {
    // wait until MY stage-t loads landed, leaving later stages in flight
    int rem = (NT - 1 - t);                       // stages ahead of t still in flight
    if (rem >= 2)      asm volatile("s_waitcnt vmcnt(6)" ::: "memory");
    else if (rem == 1) asm volatile("s_waitcnt vmcnt(3)" ::: "memory");
    else               asm volatile("s_waitcnt vmcnt(0)" ::: "memory");
    __builtin_amdgcn_s_barrier();                 // all waves' stage-t writes visible
    const int cb = t % 3;
    s16x8 a[4], bh[2], bl[2];
#pragma unroll
    for (int m = 0; m < 4; ++m)
      a[m] = *(const s16x8*)&As[cb][kq][wm * 64 + m * 16 + li][0];
#pragma unroll
    for (int n = 0; n < 2; ++n) {
      int cc = wn * 32 + n * 16 + li;
      bh[n] = *(const s16x8*)&Bsh[cb][kq][cc][0];
      bl[n] = *(const s16x8*)&Bsl[cb][kq][cc][0];
    }
    asm volatile("s_waitcnt lgkmcnt(0)" ::: "memory");  // frags in registers
    __builtin_amdgcn_sched_barrier(0);            // rule 18: pin order
    __builtin_amdgcn_s_barrier();                 // all waves done reading buf cb
    if (t + 3 < NT) stage(t + 3, cb);             // refill consumed buffer early
    __builtin_amdgcn_s_setprio(1);                // T5: favor MFMA-entering waves
#pragma unroll
    for (int m = 0; m < 4; ++m)
#pragma unroll
      for (int n = 0; n < 2; ++n) {
        acc[m][n] = __builtin_amdgcn_mfma_f32_16x16x32_bf16(a[m], bh[n], acc[m][n], 0, 0, 0);
        acc[m][n] = __builtin_amdgcn_mfma_f32_16x16x32_bf16(a[m], bl[n], acc[m][n], 0, 0, 0);
      }
    __builtin_amdgcn_s_setprio(0);
  }

  if (!POOL) {
#pragma unroll
    for (int m = 0; m < 4; ++m) {
      int rbase = row0 + wm * 64 + m * 16 + kq * 4;
#pragma unroll
      for (int n = 0; n < 2; ++n) {
        int col = col0 + wn * 32 + n * 16 + li;
        float bi = bias[col];
#pragma unroll
        for (int r = 0; r < 4; ++r) {
          int rr = rbase + r;
          if (rr < nrows)
            O[(size_t)rr * fout + col] = f2bf(fmaxf(acc[m][n][r] + bi, 0.f));
        }
      }
    }
  } else {
#pragma unroll
    for (int m = 0; m < 4; ++m) {
      int rbase = row0 + wm * 64 + m * 16 + kq * 4;
      int g4[4];
#pragma unroll
      for (int r = 0; r < 4; ++r) {
        int rr = rbase + r;
        g4[r] = (rr < nrows) ? gid[rr] : -1;
      }
#pragma unroll
      for (int n = 0; n < 2; ++n) {
        int col = col0 + wn * 32 + n * 16 + li;
        float bi = bias[col];
        float sum = 0.f; int curg = g4[0];
#pragma unroll
        for (int r = 0; r < 4; ++r) {
          if (g4[r] != curg) {
            if (curg >= 0) atomicAdd(&hg[curg * 512 + col], sum);
            sum = 0.f; curg = g4[r];
          }
          if (g4[r] >= 0) sum += fmaxf(acc[m][n][r] + bi, 0.f);
        }
        if (curg >= 0) atomicAdd(&hg[curg * 512 + col], sum);
      }
    }
  }
}

// ---------------- MLP head ----------------
__global__ void k_mlp(const float* __restrict__ hg, const float* __restrict__ Wm1,
                      const float* __restrict__ bm1, const float* __restrict__ Wm2,
                      const float* __restrict__ bm2, float* __restrict__ outp) {
  __shared__ float lh[512];
  __shared__ float lt[512];
  int g = blockIdx.x, t = threadIdx.x;
  lh[t] = hg[g * 512 + t];
  __syncthreads();
  float s = bm1[t];
  for (int k = 0; k < 512; ++k) s += lh[k] * Wm1[k * 512 + t];
  lt[t] = fmaxf(s, 0.f);
  __syncthreads();
  if (t < 10) {
    float s2 = bm2[t];
    for (int j = 0; j < 512; ++j) s2 += lt[j] * Wm2[j * 10 + t];
    outp[g * 10 + t] = s2;
  }
}

// ---------------- launch ----------------
extern "C" void kernel_launch(void* const* d_in, const int* in_sizes, int n_in,
                              void* d_out, int out_size, void* d_ws, size_t ws_size,
                              hipStream_t stream) {
  (void)in_sizes; (void)n_in; (void)out_size; (void)ws_size;
  const float* signal = (const float*)d_in[0];
  const float* W0 = (const float*)d_in[1];  const float* b0 = (const float*)d_in[2];
  const float* W1 = (const float*)d_in[3];  const float* b1 = (const float*)d_in[4];
  const float* W2 = (const float*)d_in[5];  const float* b2 = (const float*)d_in[6];
  const float* W3 = (const float*)d_in[7];  const float* b3 = (const float*)d_in[8];
  const float* Wm1 = (const float*)d_in[9];  const float* bm1 = (const float*)d_in[10];
  const float* Wm2 = (const float*)d_in[11]; const float* bm2 = (const float*)d_in[12];
  const int* src = (const int*)d_in[13];
  const int* dst = (const int*)d_in[14];
  const int* gid = (const int*)d_in[15];
  float* outp = (float*)d_out;

  char* ws = (char*)d_ws;
  size_t off = 0;
  auto alloc = [&](size_t b) -> void* {
    void* p = ws + off;
    off = (off + b + 255) & ~(size_t)255;
    return p;
  };
  // total ws footprint ~139 MB (< 145 MB proven safe in round 4)
  int* degi    = (int*)alloc((size_t)N_NODES * 4);
  float* nrm   = (float*)alloc((size_t)N_NODES * 4);
  int* rowptr  = (int*)alloc((size_t)(N_NODES + 1) * 4);
  int* cursor  = (int*)alloc((size_t)N_NODES * 4);
  int* bsum    = (int*)alloc((size_t)SCAN_G * 4);
  int* boff    = (int*)alloc((size_t)SCAN_G * 4);
  int* colidx  = (int*)alloc((size_t)N_EDGES * 4);
  float* hg    = (float*)alloc((size_t)N_GRAPH * 512 * 4);
  u16* Wth0 = (u16*)alloc((size_t)384 * 128 * 2);
  u16* Wtl0 = (u16*)alloc((size_t)384 * 128 * 2);
  u16* Wth1 = (u16*)alloc((size_t)384 * 128 * 2);
  u16* Wtl1 = (u16*)alloc((size_t)384 * 128 * 2);
  u16* Wth2 = (u16*)alloc((size_t)384 * 256 * 2);
  u16* Wtl2 = (u16*)alloc((size_t)384 * 256 * 2);
  u16* Wth3 = (u16*)alloc((size_t)768 * 512 * 2);
  u16* Wtl3 = (u16*)alloc((size_t)768 * 512 * 2);
  u16* QA = (u16*)alloc((size_t)PAD_N * 256 * 2);   // L1 out / L2 in / L3 out / L4 in
  u16* QB = (u16*)alloc((size_t)PAD_N * 128 * 2);   // sig / L2 out / L3 in / L4 Y-chunk
  u16* QX = (u16*)alloc((size_t)PAD_N * 256 * 2);   // X1 (+Y in 2nd half for F=128)

  hipMemsetAsync(degi, 0, (size_t)N_NODES * 4, stream);
  hipMemsetAsync(cursor, 0, (size_t)N_NODES * 4, stream);
  hipMemsetAsync(hg, 0, (size_t)N_GRAPH * 512 * 4, stream);

  k_deg<<<(N_EDGES + 255) / 256, 256, 0, stream>>>(dst, degi);
  k_norm<<<(N_NODES + 255) / 256, 256, 0, stream>>>(degi, nrm);
  k_scan1<<<SCAN_G, SCAN_B, 0, stream>>>(degi, rowptr, bsum);
  k_scan2<<<1, 128, 0, stream>>>(bsum, boff, rowptr);
  k_scan3<<<SCAN_G, SCAN_B, 0, stream>>>(rowptr, boff);
  k_scatter<<<(N_EDGES + 255) / 256, 256, 0, stream>>>(src, dst, rowptr, cursor, colidx);

  k_wsplit<<<(384 * 128 + 255) / 256, 256, 0, stream>>>(W0, Wth0, Wtl0, 128, 128);
  k_wsplit<<<(384 * 128 + 255) / 256, 256, 0, stream>>>(W1, Wth1, Wtl1, 128, 128);
  k_wsplit<<<(384 * 256 + 255) / 256, 256, 0, stream>>>(W2, Wth2, Wtl2, 128, 256);
  k_wsplit<<<(768 * 512 + 255) / 256, 256, 0, stream>>>(W3, Wth3, Wtl3, 256, 512);
  k_sigcast<<<(PAD_N * 128 + 255) / 256, 256, 0, stream>>>(signal, QB);

  const int gfull = (PAD_N + 3) / 4;   // ahat grid, 4 nodes per 256-thread block

  // ---- layers 1-3 (F=128): X1 = QX half0, Y = QX half1, unchunked ----
  u16* X1h = QX;
  u16* Yh  = QX + (size_t)PAD_N * 128;
  auto layer128 = [&](const u16* in, const u16* wth, const u16* wtl,
                      const float* bias, u16* outb, int fout) {
    k_ahat_bf<2><<<gfull, 256, 0, stream>>>(in,  nrm, rowptr, colidx, X1h, 128, 0, PAD_N, -1.f);
    k_ahat_bf<2><<<gfull, 256, 0, stream>>>(X1h, nrm, rowptr, colidx, Yh,  128, 0, PAD_N,  1.f);
    dim3 gg(fout / 128, PAD_N / 128);   // x = col-block, y = row-block
    k_gemm_mfma<false><<<gg, 512, 0, stream>>>(in, X1h, Yh, 128, wth, wtl, bias,
                                               outb, nullptr, nullptr, fout, N_NODES);
  };
  layer128(QB, Wth0, Wtl0, b0, QA, 128);
  layer128(QA, Wth1, Wtl1, b1, QB, 128);
  layer128(QB, Wth2, Wtl2, b2, QA, 256);

  // ---- layer 4 (F=256, fout=512, pooled): X1 = QX full; Y chunks in QB ----
  k_ahat_bf<4><<<gfull, 256, 0, stream>>>(QA, nrm, rowptr, colidx, QX, 256, 0, PAD_N, -1.f);
  const int CH4 = 50048;   // CH4*256*2 bytes == QB capacity; multiple of 128
  for (int base = 0; base < N_NODES; base += CH4) {
    int nr = (N_NODES - base < CH4) ? (N_NODES - base) : CH4;
    k_ahat_bf<4><<<(nr + 3) / 4, 256, 0, stream>>>(QX, nrm, rowptr, colidx, QB,
                                                   256, base, nr, 1.f);
    dim3 gg(4, (nr + 127) / 128);       // x = col-block, y = row-block
    k_gemm_mfma<true><<<gg, 512, 0, stream>>>(
        QA + (size_t)base * 256, QX + (size_t)base * 256, QB, 256,
        Wth3, Wtl3, b3, nullptr, hg, gid + base, 512, nr);
  }

  k_mlp<<<N_GRAPH, 512, 0, stream>>>(hg, Wm1, bm1, Wm2, bm2, outp);
}